// Round 3
// baseline (3301.955 us; speedup 1.0000x reference)
//
#include <hip/hip_runtime.h>
#include <stdint.h>

#define DGRID 8
#define NVOX  2048      // B * D^3
#define NBATCH 4
#define MMAX  1024
#define FDIM  64

// ---- float <-> order-preserving unsigned encoding (for atomic min/max) ----
__device__ __forceinline__ unsigned encf(float f){
  unsigned u = __float_as_uint(f);
  return (u & 0x80000000u) ? ~u : (u | 0x80000000u);
}
__device__ __forceinline__ float decf(unsigned e){
  unsigned u = (e & 0x80000000u) ? (e ^ 0x80000000u) : ~e;
  return __uint_as_float(u);
}

// K1: global per-dim min of pos (encoded atomicMin) + batch histogram
__global__ __launch_bounds__(256) void k_min_hist(const float* __restrict__ pos,
    const int* __restrict__ batch, int N, unsigned* startEnc, int* batchCnt){
  __shared__ int sbin[NBATCH];
  if (threadIdx.x < NBATCH) sbin[threadIdx.x] = 0;
  __syncthreads();
  unsigned m0 = 0xFFFFFFFFu, m1 = 0xFFFFFFFFu, m2 = 0xFFFFFFFFu;
  int stride = gridDim.x * blockDim.x;
  for (int i = blockIdx.x * blockDim.x + threadIdx.x; i < N; i += stride){
    unsigned e0 = encf(pos[3*i+0]); if (e0 < m0) m0 = e0;
    unsigned e1 = encf(pos[3*i+1]); if (e1 < m1) m1 = e1;
    unsigned e2 = encf(pos[3*i+2]); if (e2 < m2) m2 = e2;
    atomicAdd(&sbin[batch[i]], 1);
  }
  #pragma unroll
  for (int off = 32; off > 0; off >>= 1){
    unsigned t0 = __shfl_down(m0, off); if (t0 < m0) m0 = t0;
    unsigned t1 = __shfl_down(m1, off); if (t1 < m1) m1 = t1;
    unsigned t2 = __shfl_down(m2, off); if (t2 < m2) m2 = t2;
  }
  if ((threadIdx.x & 63) == 0){
    atomicMin(&startEnc[0], m0);
    atomicMin(&startEnc[1], m1);
    atomicMin(&startEnc[2], m2);
  }
  __syncthreads();
  if (threadIdx.x < NBATCH) atomicAdd(&batchCnt[threadIdx.x], sbin[threadIdx.x]);
}

// K2: voxel id per point (fp32, matches np-fp32 bitwise) + integer counts
__global__ __launch_bounds__(256) void k_vox(const float* __restrict__ pos,
    const int* __restrict__ batch, int N, const unsigned* __restrict__ startEnc,
    int* __restrict__ vox, int* __restrict__ counts){
  int i = blockIdx.x * blockDim.x + threadIdx.x;
  if (i >= N) return;
  // start = min - rad*0.5; fp32: 0.2f*0.5f == 0.1f exactly
  float s0 = __fsub_rn(decf(startEnc[0]), 0.1f);
  float s1 = __fsub_rn(decf(startEnc[1]), 0.1f);
  float s2 = __fsub_rn(decf(startEnc[2]), 0.1f);
  float q0 = __fdiv_rn(__fsub_rn(pos[3*i+0], s0), 0.2f);
  float q1 = __fdiv_rn(__fsub_rn(pos[3*i+1], s1), 0.2f);
  float q2 = __fdiv_rn(__fsub_rn(pos[3*i+2], s2), 0.2f);
  int c0 = (int)floorf(q0); c0 = c0 < 0 ? 0 : (c0 > DGRID-1 ? DGRID-1 : c0);
  int c1 = (int)floorf(q1); c1 = c1 < 0 ? 0 : (c1 > DGRID-1 ? DGRID-1 : c1);
  int c2 = (int)floorf(q2); c2 = c2 < 0 ? 0 : (c2 > DGRID-1 ? DGRID-1 : c2);
  int v = ((batch[i]*DGRID + c0)*DGRID + c1)*DGRID + c2;
  vox[i] = v;
  atomicAdd(&counts[v], 1);
}

// K3: single-wave scans: nonempty-voxel compaction (idxOfCluster, M),
//     per-batch cluster ranges, per-batch point ranges.
__global__ __launch_bounds__(64) void k_scan(const int* __restrict__ counts,
    const int* __restrict__ batchCnt, int* batchPtr, int* Mout,
    int* batchStartC, int* __restrict__ idxOfCluster){
  int lane = threadIdx.x;          // one wave (64)
  int cs[32];
  int ne = 0;
  #pragma unroll
  for (int j = 0; j < 32; j++){
    int c = counts[lane*32 + j];
    cs[j] = c;
    ne += (c > 0) ? 1 : 0;
  }
  int inc = ne;
  #pragma unroll
  for (int off = 1; off < 64; off <<= 1){
    int t = __shfl_up(inc, off);
    if (lane >= off) inc += t;
  }
  int exne = inc - ne;             // exclusive scan of nonempty counts
  __shared__ int laneEx[64];
  __shared__ int sM;
  laneEx[lane] = exne;
  int run = exne;
  #pragma unroll
  for (int j = 0; j < 32; j++){
    if (cs[j] > 0){
      if (run < MMAX) idxOfCluster[run] = lane*32 + j;
      run++;
    }
  }
  if (lane == 63) sM = run;
  __syncthreads();
  int M = sM;
  for (int m = M + lane; m < MMAX; m += 64) idxOfCluster[m] = 0;  // fill_value=0
  if (lane == 0){
    Mout[0] = M;
    int acc = 0;
    for (int b = 0; b < NBATCH; b++){ batchPtr[b] = acc; acc += batchCnt[b]; }
    batchPtr[NBATCH] = acc;
    for (int b = 0; b < NBATCH; b++) batchStartC[b] = laneEx[b*16]; // voxel b*512 boundary
    batchStartC[NBATCH] = (M < MMAX) ? M : MMAX;
  }
}

// K4: per-voxel fp32 position sums in EXACT point-index order (bitwise match
//     of numpy sequential scatter-add). One thread per voxel scans its
//     batch's contiguous point range (batch is sorted).
__global__ __launch_bounds__(64) void k_sum(const float* __restrict__ pos,
    const int* __restrict__ vox, const int* __restrict__ counts,
    const int* __restrict__ batchPtr, float* __restrict__ sum_pos){
  int v = blockIdx.x * 64 + threadIdx.x;
  if (v >= NVOX) return;
  int b = v >> 9;                      // voxel / 512
  int lo = batchPtr[b], hi = batchPtr[b+1];
  float sx = 0.f, sy = 0.f, sz = 0.f;
  if (counts[v] > 0){
    for (int i = lo; i < hi; i++){
      if (vox[i] == v){
        sx = __fadd_rn(sx, pos[3*i+0]);
        sy = __fadd_rn(sy, pos[3*i+1]);
        sz = __fadd_rn(sz, pos[3*i+2]);
      }
    }
  }
  sum_pos[3*v+0] = sx;
  sum_pos[3*v+1] = sy;
  sum_pos[3*v+2] = sz;
}

// K5: fp32 centroids (+ |c|^2 via sequential non-FMA sum), new_batch, valid
__global__ __launch_bounds__(256) void k_cent(const float* __restrict__ sum_pos,
    const int* __restrict__ counts, const int* __restrict__ idxOfCluster,
    const int* __restrict__ Mout, float4* __restrict__ cent4,
    float* __restrict__ outC, float* __restrict__ outNB, float* __restrict__ outValid){
  int m = blockIdx.x * blockDim.x + threadIdx.x;
  if (m >= MMAX) return;
  int M = Mout[0];
  int v = idxOfCluster[m];
  float den = fmaxf((float)counts[v], 1.0f);
  float cx = __fdiv_rn(sum_pos[3*v+0], den);
  float cy = __fdiv_rn(sum_pos[3*v+1], den);
  float cz = __fdiv_rn(sum_pos[3*v+2], den);
  // c2 = ((cx*cx + cy*cy) + cz*cz), plain sequential ops, no FMA
  float c2 = __fadd_rn(__fadd_rn(__fmul_rn(cx,cx), __fmul_rn(cy,cy)), __fmul_rn(cz,cz));
  cent4[m] = make_float4(cx, cy, cz, c2);
  outC[3*m+0] = cx; outC[3*m+1] = cy; outC[3*m+2] = cz;
  outNB[m] = (float)(v >> 9);
  outValid[m] = (m < M) ? 1.0f : 0.0f;
}

// K6: nearest same-batch centroid (first-min-index argmin) + feature atomicMax.
//     d2 = (p2 - 2*dot) + c2 with dot = ((px*cx) + (py*cy)) + (pz*cz),
//     ALL separately rounded, NO FMA — emulating non-FMA numpy fp32.
__global__ __launch_bounds__(256) void k_assign(const float* __restrict__ pos,
    const float* __restrict__ x, const int* __restrict__ batch, int N,
    const float4* __restrict__ cent4, const int* __restrict__ batchStartC,
    unsigned* __restrict__ encMax){
  __shared__ float4 sc[MMAX];         // 16 KB
  for (int m = threadIdx.x; m < MMAX; m += blockDim.x) sc[m] = cent4[m];
  __syncthreads();
  int i = blockIdx.x * blockDim.x + threadIdx.x;
  if (i >= N) return;
  float px = pos[3*i+0], py = pos[3*i+1], pz = pos[3*i+2];
  float p2 = __fadd_rn(__fadd_rn(__fmul_rn(px,px), __fmul_rn(py,py)), __fmul_rn(pz,pz));
  int b = batch[i];
  int mlo = batchStartC[b], mhi = batchStartC[b+1];
  float best = 3.402823466e+38f;
  int bm = mlo;
  for (int m = mlo; m < mhi; m++){
    float4 c = sc[m];
    float dot = __fadd_rn(__fadd_rn(__fmul_rn(px,c.x), __fmul_rn(py,c.y)),
                          __fmul_rn(pz,c.z));
    float d2  = __fadd_rn(__fsub_rn(p2, __fmul_rn(2.0f, dot)), c.w);
    if (d2 < best){ best = d2; bm = m; }
  }
  unsigned* dst = encMax + bm * FDIM;
  const float4* xi = (const float4*)(x + (size_t)i * FDIM);
  #pragma unroll
  for (int f4 = 0; f4 < FDIM/4; f4++){
    float4 xv = xi[f4];
    atomicMax(&dst[4*f4+0], encf(xv.x));
    atomicMax(&dst[4*f4+1], encf(xv.y));
    atomicMax(&dst[4*f4+2], encf(xv.z));
    atomicMax(&dst[4*f4+3], encf(xv.w));
  }
}

// K7: decode encoded maxima; enc==0 sentinel -> 0 (never-assigned / padded)
__global__ __launch_bounds__(256) void k_decode(const unsigned* __restrict__ encMax,
    float* __restrict__ outX){
  int t = blockIdx.x * blockDim.x + threadIdx.x;
  if (t >= MMAX * FDIM) return;
  unsigned e = encMax[t];
  outX[t] = (e == 0u) ? 0.0f : decf(e);
}

// ---- workspace layout (bytes) ----
// 0      : startEnc      3 x u32   (memset 0xFF)
// 16     : batchCnt      4 x i32   (memset 0)
// 32     : batchPtr      5 x i32
// 64     : Mout          1 x i32
// 80     : batchStartC   5 x i32
// 128    : counts        2048 x i32 (memset 0)
// 8320   : sum_pos       2048 x 3 x f32 (24576 B)
// 32896  : idxOfCluster  1024 x i32
// 36992  : cent4         1024 x float4 (16384 B)
// 53376  : encMax        1024 x 64 x u32 (memset 0, 262144 B)
// 315520 : vox           N x i32
// total ~716 KB

extern "C" void kernel_launch(void* const* d_in, const int* in_sizes, int n_in,
                              void* d_out, int out_size, void* d_ws, size_t ws_size,
                              hipStream_t stream){
  const float* pos   = (const float*)d_in[0];
  const float* x     = (const float*)d_in[1];
  const int*   batch = (const int*)d_in[2];
  const int N = in_sizes[2];

  char* w = (char*)d_ws;
  unsigned* startEnc     = (unsigned*)(w + 0);
  int*      batchCnt     = (int*)(w + 16);
  int*      batchPtr     = (int*)(w + 32);
  int*      Mout         = (int*)(w + 64);
  int*      batchStartC  = (int*)(w + 80);
  int*      counts       = (int*)(w + 128);
  float*    sum_pos      = (float*)(w + 8320);
  int*      idxOfCluster = (int*)(w + 32896);
  float4*   cent4        = (float4*)(w + 36992);
  unsigned* encMax       = (unsigned*)(w + 53376);
  int*      vox          = (int*)(w + 315520);

  float* outX     = (float*)d_out;          // [1024,64]
  float* outC     = outX + MMAX * FDIM;     // [1024,3]
  float* outNB    = outC + MMAX * 3;        // [1024]
  float* outValid = outNB + MMAX;           // [1024]

  hipMemsetAsync(startEnc, 0xFF, 12, stream);
  hipMemsetAsync(batchCnt, 0, 16, stream);
  hipMemsetAsync(counts, 0, NVOX * 4, stream);
  hipMemsetAsync(encMax, 0, MMAX * FDIM * 4, stream);

  const int nb = (N + 255) / 256;
  k_min_hist<<<256, 256, 0, stream>>>(pos, batch, N, startEnc, batchCnt);
  k_vox<<<nb, 256, 0, stream>>>(pos, batch, N, startEnc, vox, counts);
  k_scan<<<1, 64, 0, stream>>>(counts, batchCnt, batchPtr, Mout, batchStartC, idxOfCluster);
  k_sum<<<(NVOX + 63) / 64, 64, 0, stream>>>(pos, vox, counts, batchPtr, sum_pos);
  k_cent<<<(MMAX + 255) / 256, 256, 0, stream>>>(sum_pos, counts, idxOfCluster, Mout,
                                                 cent4, outC, outNB, outValid);
  k_assign<<<nb, 256, 0, stream>>>(pos, x, batch, N, cent4, batchStartC, encMax);
  k_decode<<<(MMAX * FDIM + 255) / 256, 256, 0, stream>>>(encMax, outX);
}

// Round 4
// 543.719 us; speedup vs baseline: 6.0729x; 6.0729x over previous
//
#include <hip/hip_runtime.h>
#include <stdint.h>

#define DGRID 8
#define NVOX  2048      // B * D^3
#define NBATCH 4
#define MMAX  1024
#define FDIM  64
#define CHUNK 1024      // points per sort chunk

// ---- float <-> order-preserving unsigned encoding (for atomic min/max) ----
__device__ __forceinline__ unsigned encf(float f){
  unsigned u = __float_as_uint(f);
  return (u & 0x80000000u) ? ~u : (u | 0x80000000u);
}
__device__ __forceinline__ float decf(unsigned e){
  unsigned u = (e & 0x80000000u) ? (e ^ 0x80000000u) : ~e;
  return __uint_as_float(u);
}

// K1: global per-dim min of pos (encoded atomicMin) + batch histogram
__global__ __launch_bounds__(256) void k_min_hist(const float* __restrict__ pos,
    const int* __restrict__ batch, int N, unsigned* startEnc, int* batchCnt){
  __shared__ int sbin[NBATCH];
  if (threadIdx.x < NBATCH) sbin[threadIdx.x] = 0;
  __syncthreads();
  unsigned m0 = 0xFFFFFFFFu, m1 = 0xFFFFFFFFu, m2 = 0xFFFFFFFFu;
  int stride = gridDim.x * blockDim.x;
  for (int i = blockIdx.x * blockDim.x + threadIdx.x; i < N; i += stride){
    unsigned e0 = encf(pos[3*i+0]); if (e0 < m0) m0 = e0;
    unsigned e1 = encf(pos[3*i+1]); if (e1 < m1) m1 = e1;
    unsigned e2 = encf(pos[3*i+2]); if (e2 < m2) m2 = e2;
    atomicAdd(&sbin[batch[i]], 1);
  }
  #pragma unroll
  for (int off = 32; off > 0; off >>= 1){
    unsigned t0 = __shfl_down(m0, off); if (t0 < m0) m0 = t0;
    unsigned t1 = __shfl_down(m1, off); if (t1 < m1) m1 = t1;
    unsigned t2 = __shfl_down(m2, off); if (t2 < m2) m2 = t2;
  }
  if ((threadIdx.x & 63) == 0){
    atomicMin(&startEnc[0], m0);
    atomicMin(&startEnc[1], m1);
    atomicMin(&startEnc[2], m2);
  }
  __syncthreads();
  if (threadIdx.x < NBATCH) atomicAdd(&batchCnt[threadIdx.x], sbin[threadIdx.x]);
}

// K2: voxel id per point (fp32, matches np-fp32 bitwise) + integer counts
__global__ __launch_bounds__(256) void k_vox(const float* __restrict__ pos,
    const int* __restrict__ batch, int N, const unsigned* __restrict__ startEnc,
    int* __restrict__ vox, int* __restrict__ counts){
  int i = blockIdx.x * blockDim.x + threadIdx.x;
  if (i >= N) return;
  float s0 = __fsub_rn(decf(startEnc[0]), 0.1f);
  float s1 = __fsub_rn(decf(startEnc[1]), 0.1f);
  float s2 = __fsub_rn(decf(startEnc[2]), 0.1f);
  float q0 = __fdiv_rn(__fsub_rn(pos[3*i+0], s0), 0.2f);
  float q1 = __fdiv_rn(__fsub_rn(pos[3*i+1], s1), 0.2f);
  float q2 = __fdiv_rn(__fsub_rn(pos[3*i+2], s2), 0.2f);
  int c0 = (int)floorf(q0); c0 = c0 < 0 ? 0 : (c0 > DGRID-1 ? DGRID-1 : c0);
  int c1 = (int)floorf(q1); c1 = c1 < 0 ? 0 : (c1 > DGRID-1 ? DGRID-1 : c1);
  int c2 = (int)floorf(q2); c2 = c2 < 0 ? 0 : (c2 > DGRID-1 ? DGRID-1 : c2);
  int v = ((batch[i]*DGRID + c0)*DGRID + c1)*DGRID + c2;
  vox[i] = v;
  atomicAdd(&counts[v], 1);
}

// K2b: per-chunk voxel histogram (for stable counting sort)
__global__ __launch_bounds__(256) void k_chist(const int* __restrict__ vox, int N,
    int* __restrict__ chunkHist){
  __shared__ int h[NVOX];
  for (int t = threadIdx.x; t < NVOX; t += 256) h[t] = 0;
  __syncthreads();
  int c = blockIdx.x;
  int lo = c * CHUNK, hi = min(N, lo + CHUNK);
  for (int i = lo + threadIdx.x; i < hi; i += 256)
    atomicAdd(&h[vox[i]], 1);
  __syncthreads();
  for (int t = threadIdx.x; t < NVOX; t += 256)
    chunkHist[c * NVOX + t] = h[t];
}

// K3: single-wave scans: nonempty compaction, per-batch ranges, AND
//     exclusive prefix sum of counts -> voxBase (for counting sort).
__global__ __launch_bounds__(64) void k_scan(const int* __restrict__ counts,
    const int* __restrict__ batchCnt, int* batchPtr, int* Mout,
    int* batchStartC, int* __restrict__ idxOfCluster, int* __restrict__ voxBase){
  int lane = threadIdx.x;          // one wave (64)
  int cs[32];
  int ne = 0, tot = 0;
  #pragma unroll
  for (int j = 0; j < 32; j++){
    int c = counts[lane*32 + j];
    cs[j] = c;
    ne += (c > 0) ? 1 : 0;
    tot += c;
  }
  int inc = ne, incT = tot;
  #pragma unroll
  for (int off = 1; off < 64; off <<= 1){
    int t  = __shfl_up(inc,  off);
    int tt = __shfl_up(incT, off);
    if (lane >= off){ inc += t; incT += tt; }
  }
  int exne = inc - ne;             // exclusive scan of nonempty counts
  int bb   = incT - tot;           // exclusive scan of total counts
  __shared__ int laneEx[64];
  __shared__ int sM;
  laneEx[lane] = exne;
  int run = exne;
  #pragma unroll
  for (int j = 0; j < 32; j++){
    voxBase[lane*32 + j] = bb;
    bb += cs[j];
    if (cs[j] > 0){
      if (run < MMAX) idxOfCluster[run] = lane*32 + j;
      run++;
    }
  }
  if (lane == 63) sM = run;
  __syncthreads();
  int M = sM;
  for (int m = M + lane; m < MMAX; m += 64) idxOfCluster[m] = 0;  // fill_value=0
  if (lane == 0){
    Mout[0] = M;
    int acc = 0;
    for (int b = 0; b < NBATCH; b++){ batchPtr[b] = acc; acc += batchCnt[b]; }
    batchPtr[NBATCH] = acc;
    for (int b = 0; b < NBATCH; b++) batchStartC[b] = laneEx[b*16]; // voxel b*512 boundary
    batchStartC[NBATCH] = (M < MMAX) ? M : MMAX;
  }
}

// K3b: column scan: chunkHist[c][v] := voxBase[v] + sum_{c'<c} chunkHist[c'][v]
__global__ __launch_bounds__(256) void k_colscan(const int* __restrict__ voxBase,
    int nchunks, int* __restrict__ chunkHist){
  int v = blockIdx.x * 256 + threadIdx.x;
  if (v >= NVOX) return;
  int run = voxBase[v];
  for (int c = 0; c < nchunks; c++){
    int t = chunkHist[c * NVOX + v];
    chunkHist[c * NVOX + v] = run;
    run += t;
  }
}

// K3c: stable scatter of pos into voxel-sorted order. One wave per chunk;
//      in-wave stable rank via shfl match loop; LDS per-voxel cursors.
__global__ __launch_bounds__(64) void k_scatter(const float* __restrict__ pos,
    const int* __restrict__ vox, int N, const int* __restrict__ chunkHist,
    float* __restrict__ pos_sorted){
  __shared__ int cur[NVOX];
  int c = blockIdx.x, lane = threadIdx.x;
  for (int t = lane; t < NVOX; t += 64) cur[t] = chunkHist[c * NVOX + t];
  __syncthreads();
  int lo = c * CHUNK;
  for (int r = 0; r < CHUNK/64; r++){
    int i = lo + r*64 + lane;
    bool valid = i < N;
    int v = valid ? vox[i] : -1;
    float px = 0.f, py = 0.f, pz = 0.f;
    if (valid){ px = pos[3*i+0]; py = pos[3*i+1]; pz = pos[3*i+2]; }
    int rank = 0, cnt = 0, leader = -1;
    #pragma unroll 8
    for (int j = 0; j < 64; j++){
      int vj = __shfl(v, j);
      if (vj == v){
        cnt++;
        if (j < lane) rank++;
        if (leader < 0) leader = j;
      }
    }
    int old = 0;
    if (valid && rank == 0) old = atomicAdd(&cur[v], cnt);
    int base = __shfl(old, leader);
    if (valid){
      int dst = base + rank;
      pos_sorted[3*dst+0] = px;
      pos_sorted[3*dst+1] = py;
      pos_sorted[3*dst+2] = pz;
    }
  }
}

// K4-fast: per-voxel fp32 sums over the voxel's contiguous sorted run.
// Stable sort preserves original index order within each voxel, so the
// sequential __fadd_rn chain is BITWISE identical to the slow path / numpy.
__global__ __launch_bounds__(256) void k_sum2(const float* __restrict__ pos_sorted,
    const int* __restrict__ voxBase, const int* __restrict__ counts,
    float* __restrict__ sum_pos){
  int v = blockIdx.x * 256 + threadIdx.x;
  if (v >= NVOX) return;
  int lo = voxBase[v], cnt = counts[v];
  float sx = 0.f, sy = 0.f, sz = 0.f;
  for (int k = 0; k < cnt; k++){
    sx = __fadd_rn(sx, pos_sorted[3*(lo+k)+0]);
    sy = __fadd_rn(sy, pos_sorted[3*(lo+k)+1]);
    sz = __fadd_rn(sz, pos_sorted[3*(lo+k)+2]);
  }
  sum_pos[3*v+0] = sx;
  sum_pos[3*v+1] = sy;
  sum_pos[3*v+2] = sz;
}

// K4-slow fallback (ws too small): exact point-order scan per voxel
__global__ __launch_bounds__(64) void k_sum(const float* __restrict__ pos,
    const int* __restrict__ vox, const int* __restrict__ counts,
    const int* __restrict__ batchPtr, float* __restrict__ sum_pos){
  int v = blockIdx.x * 64 + threadIdx.x;
  if (v >= NVOX) return;
  int b = v >> 9;
  int lo = batchPtr[b], hi = batchPtr[b+1];
  float sx = 0.f, sy = 0.f, sz = 0.f;
  if (counts[v] > 0){
    for (int i = lo; i < hi; i++){
      if (vox[i] == v){
        sx = __fadd_rn(sx, pos[3*i+0]);
        sy = __fadd_rn(sy, pos[3*i+1]);
        sz = __fadd_rn(sz, pos[3*i+2]);
      }
    }
  }
  sum_pos[3*v+0] = sx;
  sum_pos[3*v+1] = sy;
  sum_pos[3*v+2] = sz;
}

// K5: fp32 centroids (+ |c|^2 via sequential non-FMA sum), new_batch, valid
__global__ __launch_bounds__(256) void k_cent(const float* __restrict__ sum_pos,
    const int* __restrict__ counts, const int* __restrict__ idxOfCluster,
    const int* __restrict__ Mout, float4* __restrict__ cent4,
    float* __restrict__ outC, float* __restrict__ outNB, float* __restrict__ outValid){
  int m = blockIdx.x * blockDim.x + threadIdx.x;
  if (m >= MMAX) return;
  int M = Mout[0];
  int v = idxOfCluster[m];
  float den = fmaxf((float)counts[v], 1.0f);
  float cx = __fdiv_rn(sum_pos[3*v+0], den);
  float cy = __fdiv_rn(sum_pos[3*v+1], den);
  float cz = __fdiv_rn(sum_pos[3*v+2], den);
  float c2 = __fadd_rn(__fadd_rn(__fmul_rn(cx,cx), __fmul_rn(cy,cy)), __fmul_rn(cz,cz));
  cent4[m] = make_float4(cx, cy, cz, c2);
  outC[3*m+0] = cx; outC[3*m+1] = cy; outC[3*m+2] = cz;
  outNB[m] = (float)(v >> 9);
  outValid[m] = (m < M) ? 1.0f : 0.0f;
}

// K6: nearest same-batch centroid (first-min-index argmin) + feature atomicMax.
//     d2 = (p2 - 2*dot) + c2, dot = ((px*cx)+(py*cy))+(pz*cz), NO FMA.
__global__ __launch_bounds__(256) void k_assign(const float* __restrict__ pos,
    const float* __restrict__ x, const int* __restrict__ batch, int N,
    const float4* __restrict__ cent4, const int* __restrict__ batchStartC,
    unsigned* __restrict__ encMax){
  __shared__ float4 sc[MMAX];         // 16 KB
  for (int m = threadIdx.x; m < MMAX; m += blockDim.x) sc[m] = cent4[m];
  __syncthreads();
  int i = blockIdx.x * blockDim.x + threadIdx.x;
  if (i >= N) return;
  float px = pos[3*i+0], py = pos[3*i+1], pz = pos[3*i+2];
  float p2 = __fadd_rn(__fadd_rn(__fmul_rn(px,px), __fmul_rn(py,py)), __fmul_rn(pz,pz));
  int b = batch[i];
  int mlo = batchStartC[b], mhi = batchStartC[b+1];
  float best = 3.402823466e+38f;
  int bm = mlo;
  for (int m = mlo; m < mhi; m++){
    float4 c = sc[m];
    float dot = __fadd_rn(__fadd_rn(__fmul_rn(px,c.x), __fmul_rn(py,c.y)),
                          __fmul_rn(pz,c.z));
    float d2  = __fadd_rn(__fsub_rn(p2, __fmul_rn(2.0f, dot)), c.w);
    if (d2 < best){ best = d2; bm = m; }
  }
  unsigned* dst = encMax + bm * FDIM;
  const float4* xi = (const float4*)(x + (size_t)i * FDIM);
  #pragma unroll
  for (int f4 = 0; f4 < FDIM/4; f4++){
    float4 xv = xi[f4];
    atomicMax(&dst[4*f4+0], encf(xv.x));
    atomicMax(&dst[4*f4+1], encf(xv.y));
    atomicMax(&dst[4*f4+2], encf(xv.z));
    atomicMax(&dst[4*f4+3], encf(xv.w));
  }
}

// K7: decode encoded maxima; enc==0 sentinel -> 0 (never-assigned / padded)
__global__ __launch_bounds__(256) void k_decode(const unsigned* __restrict__ encMax,
    float* __restrict__ outX){
  int t = blockIdx.x * blockDim.x + threadIdx.x;
  if (t >= MMAX * FDIM) return;
  unsigned e = encMax[t];
  outX[t] = (e == 0u) ? 0.0f : decf(e);
}

// ---- workspace layout (bytes) ----
// 0      : startEnc      3 x u32   (memset 0xFF)
// 16     : batchCnt      4 x i32   (memset 0)
// 32     : batchPtr      5 x i32
// 64     : Mout          1 x i32
// 80     : batchStartC   5 x i32
// 128    : counts        2048 x i32 (memset 0)
// 8320   : voxBase       2048 x i32
// 16512  : sum_pos       2048 x 3 x f32
// 41088  : idxOfCluster  1024 x i32
// 45184  : cent4         1024 x float4
// 61568  : encMax        1024 x 64 x u32 (memset 0)
// 323712 : vox           N x i32
// then   : chunkHist     nchunks x 2048 x i32
// then   : pos_sorted    N x 3 x f32

extern "C" void kernel_launch(void* const* d_in, const int* in_sizes, int n_in,
                              void* d_out, int out_size, void* d_ws, size_t ws_size,
                              hipStream_t stream){
  const float* pos   = (const float*)d_in[0];
  const float* x     = (const float*)d_in[1];
  const int*   batch = (const int*)d_in[2];
  const int N = in_sizes[2];
  const int nchunks = (N + CHUNK - 1) / CHUNK;

  char* w = (char*)d_ws;
  unsigned* startEnc     = (unsigned*)(w + 0);
  int*      batchCnt     = (int*)(w + 16);
  int*      batchPtr     = (int*)(w + 32);
  int*      Mout         = (int*)(w + 64);
  int*      batchStartC  = (int*)(w + 80);
  int*      counts       = (int*)(w + 128);
  int*      voxBase      = (int*)(w + 8320);
  float*    sum_pos      = (float*)(w + 16512);
  int*      idxOfCluster = (int*)(w + 41088);
  float4*   cent4        = (float4*)(w + 45184);
  unsigned* encMax       = (unsigned*)(w + 61568);
  int*      vox          = (int*)(w + 323712);
  size_t voxEnd = 323712 + (size_t)N * 4;
  size_t chOff  = (voxEnd + 15) & ~(size_t)15;
  int*      chunkHist    = (int*)(w + chOff);
  size_t psOff  = chOff + (size_t)nchunks * NVOX * 4;
  float*    pos_sorted   = (float*)(w + psOff);
  size_t need = psOff + (size_t)N * 3 * 4;
  const bool fast = (ws_size >= need);

  float* outX     = (float*)d_out;          // [1024,64]
  float* outC     = outX + MMAX * FDIM;     // [1024,3]
  float* outNB    = outC + MMAX * 3;        // [1024]
  float* outValid = outNB + MMAX;           // [1024]

  hipMemsetAsync(startEnc, 0xFF, 12, stream);
  hipMemsetAsync(batchCnt, 0, 16, stream);
  hipMemsetAsync(counts, 0, NVOX * 4, stream);
  hipMemsetAsync(encMax, 0, MMAX * FDIM * 4, stream);

  const int nb = (N + 255) / 256;
  k_min_hist<<<256, 256, 0, stream>>>(pos, batch, N, startEnc, batchCnt);
  k_vox<<<nb, 256, 0, stream>>>(pos, batch, N, startEnc, vox, counts);
  k_scan<<<1, 64, 0, stream>>>(counts, batchCnt, batchPtr, Mout, batchStartC,
                               idxOfCluster, voxBase);
  if (fast){
    k_chist<<<nchunks, 256, 0, stream>>>(vox, N, chunkHist);
    k_colscan<<<NVOX / 256, 256, 0, stream>>>(voxBase, nchunks, chunkHist);
    k_scatter<<<nchunks, 64, 0, stream>>>(pos, vox, N, chunkHist, pos_sorted);
    k_sum2<<<NVOX / 256, 256, 0, stream>>>(pos_sorted, voxBase, counts, sum_pos);
  } else {
    k_sum<<<(NVOX + 63) / 64, 64, 0, stream>>>(pos, vox, counts, batchPtr, sum_pos);
  }
  k_cent<<<(MMAX + 255) / 256, 256, 0, stream>>>(sum_pos, counts, idxOfCluster, Mout,
                                                 cent4, outC, outNB, outValid);
  k_assign<<<nb, 256, 0, stream>>>(pos, x, batch, N, cent4, batchStartC, encMax);
  k_decode<<<(MMAX * FDIM + 255) / 256, 256, 0, stream>>>(encMax, outX);
}

// Round 5
// 382.676 us; speedup vs baseline: 8.6286x; 1.4208x over previous
//
#include <hip/hip_runtime.h>
#include <stdint.h>

#define DGRID 8
#define NVOX  2048      // B * D^3
#define NBATCH 4
#define MMAX  1024
#define FDIM  64
#define CHUNK 1024      // points per sort chunk

// ---- float <-> order-preserving unsigned encoding (for atomic min/max) ----
__device__ __forceinline__ unsigned encf(float f){
  unsigned u = __float_as_uint(f);
  return (u & 0x80000000u) ? ~u : (u | 0x80000000u);
}
__device__ __forceinline__ float decf(unsigned e){
  unsigned u = (e & 0x80000000u) ? (e ^ 0x80000000u) : ~e;
  return __uint_as_float(u);
}

// K1: global per-dim min of pos (encoded atomicMin) + batch histogram
__global__ __launch_bounds__(256) void k_min_hist(const float* __restrict__ pos,
    const int* __restrict__ batch, int N, unsigned* startEnc, int* batchCnt){
  __shared__ int sbin[NBATCH];
  if (threadIdx.x < NBATCH) sbin[threadIdx.x] = 0;
  __syncthreads();
  unsigned m0 = 0xFFFFFFFFu, m1 = 0xFFFFFFFFu, m2 = 0xFFFFFFFFu;
  int stride = gridDim.x * blockDim.x;
  for (int i = blockIdx.x * blockDim.x + threadIdx.x; i < N; i += stride){
    unsigned e0 = encf(pos[3*i+0]); if (e0 < m0) m0 = e0;
    unsigned e1 = encf(pos[3*i+1]); if (e1 < m1) m1 = e1;
    unsigned e2 = encf(pos[3*i+2]); if (e2 < m2) m2 = e2;
    atomicAdd(&sbin[batch[i]], 1);
  }
  #pragma unroll
  for (int off = 32; off > 0; off >>= 1){
    unsigned t0 = __shfl_down(m0, off); if (t0 < m0) m0 = t0;
    unsigned t1 = __shfl_down(m1, off); if (t1 < m1) m1 = t1;
    unsigned t2 = __shfl_down(m2, off); if (t2 < m2) m2 = t2;
  }
  if ((threadIdx.x & 63) == 0){
    atomicMin(&startEnc[0], m0);
    atomicMin(&startEnc[1], m1);
    atomicMin(&startEnc[2], m2);
  }
  __syncthreads();
  if (threadIdx.x < NBATCH) atomicAdd(&batchCnt[threadIdx.x], sbin[threadIdx.x]);
}

// common fp32 voxel-coord computation (bitwise np-fp32 emulation)
__device__ __forceinline__ int voxel_of(const float* pos, int i, int b,
                                        const unsigned* startEnc){
  float s0 = __fsub_rn(decf(startEnc[0]), 0.1f);
  float s1 = __fsub_rn(decf(startEnc[1]), 0.1f);
  float s2 = __fsub_rn(decf(startEnc[2]), 0.1f);
  float q0 = __fdiv_rn(__fsub_rn(pos[3*i+0], s0), 0.2f);
  float q1 = __fdiv_rn(__fsub_rn(pos[3*i+1], s1), 0.2f);
  float q2 = __fdiv_rn(__fsub_rn(pos[3*i+2], s2), 0.2f);
  int c0 = (int)floorf(q0); c0 = c0 < 0 ? 0 : (c0 > DGRID-1 ? DGRID-1 : c0);
  int c1 = (int)floorf(q1); c1 = c1 < 0 ? 0 : (c1 > DGRID-1 ? DGRID-1 : c1);
  int c2 = (int)floorf(q2); c2 = c2 < 0 ? 0 : (c2 > DGRID-1 ? DGRID-1 : c2);
  return ((b*DGRID + c0)*DGRID + c1)*DGRID + c2;
}

// K2-fast: voxel id per point, no global atomics (counts from colscan)
__global__ __launch_bounds__(256) void k_vox2(const float* __restrict__ pos,
    const int* __restrict__ batch, int N, const unsigned* __restrict__ startEnc,
    int* __restrict__ vox){
  int i = blockIdx.x * blockDim.x + threadIdx.x;
  if (i >= N) return;
  vox[i] = voxel_of(pos, i, batch[i], startEnc);
}

// K2-slow fallback: voxel id + atomic counts
__global__ __launch_bounds__(256) void k_vox(const float* __restrict__ pos,
    const int* __restrict__ batch, int N, const unsigned* __restrict__ startEnc,
    int* __restrict__ vox, int* __restrict__ counts){
  int i = blockIdx.x * blockDim.x + threadIdx.x;
  if (i >= N) return;
  int v = voxel_of(pos, i, batch[i], startEnc);
  vox[i] = v;
  atomicAdd(&counts[v], 1);
}

// K2b: per-chunk voxel histogram (for stable counting sort)
__global__ __launch_bounds__(256) void k_chist(const int* __restrict__ vox, int N,
    int* __restrict__ chunkHist){
  __shared__ int h[NVOX];
  for (int t = threadIdx.x; t < NVOX; t += 256) h[t] = 0;
  __syncthreads();
  int c = blockIdx.x;
  int lo = c * CHUNK, hi = min(N, lo + CHUNK);
  for (int i = lo + threadIdx.x; i < hi; i += 256)
    atomicAdd(&h[vox[i]], 1);
  __syncthreads();
  for (int t = threadIdx.x; t < NVOX; t += 256)
    chunkHist[c * NVOX + t] = h[t];
}

// K2c: in-place exclusive column prefix over chunks; emits total -> counts[v]
__global__ __launch_bounds__(256) void k_colscan(int nchunks,
    int* __restrict__ chunkHist, int* __restrict__ counts){
  int v = blockIdx.x * 256 + threadIdx.x;
  if (v >= NVOX) return;
  int run = 0;
  for (int c = 0; c < nchunks; c++){
    int t = chunkHist[c * NVOX + v];
    chunkHist[c * NVOX + v] = run;
    run += t;
  }
  counts[v] = run;
}

// K3: single-wave scans: nonempty compaction, per-batch ranges, AND
//     exclusive prefix sum of counts -> voxBase (for counting sort).
__global__ __launch_bounds__(64) void k_scan(const int* __restrict__ counts,
    const int* __restrict__ batchCnt, int* batchPtr, int* Mout,
    int* batchStartC, int* __restrict__ idxOfCluster, int* __restrict__ voxBase){
  int lane = threadIdx.x;          // one wave (64)
  int cs[32];
  int ne = 0, tot = 0;
  #pragma unroll
  for (int j = 0; j < 32; j++){
    int c = counts[lane*32 + j];
    cs[j] = c;
    ne += (c > 0) ? 1 : 0;
    tot += c;
  }
  int inc = ne, incT = tot;
  #pragma unroll
  for (int off = 1; off < 64; off <<= 1){
    int t  = __shfl_up(inc,  off);
    int tt = __shfl_up(incT, off);
    if (lane >= off){ inc += t; incT += tt; }
  }
  int exne = inc - ne;             // exclusive scan of nonempty counts
  int bb   = incT - tot;           // exclusive scan of total counts
  __shared__ int laneEx[64];
  __shared__ int sM;
  laneEx[lane] = exne;
  int run = exne;
  #pragma unroll
  for (int j = 0; j < 32; j++){
    voxBase[lane*32 + j] = bb;
    bb += cs[j];
    if (cs[j] > 0){
      if (run < MMAX) idxOfCluster[run] = lane*32 + j;
      run++;
    }
  }
  if (lane == 63) sM = run;
  __syncthreads();
  int M = sM;
  for (int m = M + lane; m < MMAX; m += 64) idxOfCluster[m] = 0;  // fill_value=0
  if (lane == 0){
    Mout[0] = M;
    int acc = 0;
    for (int b = 0; b < NBATCH; b++){ batchPtr[b] = acc; acc += batchCnt[b]; }
    batchPtr[NBATCH] = acc;
    for (int b = 0; b < NBATCH; b++) batchStartC[b] = laneEx[b*16]; // voxel b*512 boundary
    batchStartC[NBATCH] = (M < MMAX) ? M : MMAX;
  }
}

// K3c: stable scatter of pos into voxel-sorted order. One wave per chunk;
//      in-wave stable rank via shfl match loop; LDS per-voxel cursors.
__global__ __launch_bounds__(64) void k_scatter(const float* __restrict__ pos,
    const int* __restrict__ vox, int N, const int* __restrict__ chunkHist,
    const int* __restrict__ voxBase, float* __restrict__ pos_sorted){
  __shared__ int cur[NVOX];
  int c = blockIdx.x, lane = threadIdx.x;
  for (int t = lane; t < NVOX; t += 64) cur[t] = chunkHist[c * NVOX + t] + voxBase[t];
  __syncthreads();
  int lo = c * CHUNK;
  for (int r = 0; r < CHUNK/64; r++){
    int i = lo + r*64 + lane;
    bool valid = i < N;
    int v = valid ? vox[i] : -1;
    float px = 0.f, py = 0.f, pz = 0.f;
    if (valid){ px = pos[3*i+0]; py = pos[3*i+1]; pz = pos[3*i+2]; }
    int rank = 0, cnt = 0, leader = -1;
    #pragma unroll 8
    for (int j = 0; j < 64; j++){
      int vj = __shfl(v, j);
      if (vj == v){
        cnt++;
        if (j < lane) rank++;
        if (leader < 0) leader = j;
      }
    }
    int old = 0;
    if (valid && rank == 0) old = atomicAdd(&cur[v], cnt);
    int base = __shfl(old, leader);
    if (valid){
      int dst = base + rank;
      pos_sorted[3*dst+0] = px;
      pos_sorted[3*dst+1] = py;
      pos_sorted[3*dst+2] = pz;
    }
  }
}

// K4-fast: per-voxel fp32 sums over the voxel's contiguous sorted run.
// Stable sort preserves original index order within each voxel, so the
// sequential __fadd_rn chain is BITWISE identical to numpy's scatter-add.
__global__ __launch_bounds__(256) void k_sum2(const float* __restrict__ pos_sorted,
    const int* __restrict__ voxBase, const int* __restrict__ counts,
    float* __restrict__ sum_pos){
  int v = blockIdx.x * 256 + threadIdx.x;
  if (v >= NVOX) return;
  int lo = voxBase[v], cnt = counts[v];
  float sx = 0.f, sy = 0.f, sz = 0.f;
  for (int k = 0; k < cnt; k++){
    sx = __fadd_rn(sx, pos_sorted[3*(lo+k)+0]);
    sy = __fadd_rn(sy, pos_sorted[3*(lo+k)+1]);
    sz = __fadd_rn(sz, pos_sorted[3*(lo+k)+2]);
  }
  sum_pos[3*v+0] = sx;
  sum_pos[3*v+1] = sy;
  sum_pos[3*v+2] = sz;
}

// K4-slow fallback (ws too small): exact point-order scan per voxel
__global__ __launch_bounds__(64) void k_sum(const float* __restrict__ pos,
    const int* __restrict__ vox, const int* __restrict__ counts,
    const int* __restrict__ batchPtr, float* __restrict__ sum_pos){
  int v = blockIdx.x * 64 + threadIdx.x;
  if (v >= NVOX) return;
  int b = v >> 9;
  int lo = batchPtr[b], hi = batchPtr[b+1];
  float sx = 0.f, sy = 0.f, sz = 0.f;
  if (counts[v] > 0){
    for (int i = lo; i < hi; i++){
      if (vox[i] == v){
        sx = __fadd_rn(sx, pos[3*i+0]);
        sy = __fadd_rn(sy, pos[3*i+1]);
        sz = __fadd_rn(sz, pos[3*i+2]);
      }
    }
  }
  sum_pos[3*v+0] = sx;
  sum_pos[3*v+1] = sy;
  sum_pos[3*v+2] = sz;
}

// K5: fp32 centroids (+ |c|^2 via sequential non-FMA sum), new_batch, valid
__global__ __launch_bounds__(256) void k_cent(const float* __restrict__ sum_pos,
    const int* __restrict__ counts, const int* __restrict__ idxOfCluster,
    const int* __restrict__ Mout, float4* __restrict__ cent4,
    float* __restrict__ outC, float* __restrict__ outNB, float* __restrict__ outValid){
  int m = blockIdx.x * blockDim.x + threadIdx.x;
  if (m >= MMAX) return;
  int M = Mout[0];
  int v = idxOfCluster[m];
  float den = fmaxf((float)counts[v], 1.0f);
  float cx = __fdiv_rn(sum_pos[3*v+0], den);
  float cy = __fdiv_rn(sum_pos[3*v+1], den);
  float cz = __fdiv_rn(sum_pos[3*v+2], den);
  float c2 = __fadd_rn(__fadd_rn(__fmul_rn(cx,cx), __fmul_rn(cy,cy)), __fmul_rn(cz,cz));
  cent4[m] = make_float4(cx, cy, cz, c2);
  outC[3*m+0] = cx; outC[3*m+1] = cy; outC[3*m+2] = cz;
  outNB[m] = (float)(v >> 9);
  outValid[m] = (m < M) ? 1.0f : 0.0f;
}

// K6-fast: argmin only (EXACT same fp32 code as before), writes assign[] and
//          per-chunk cluster histogram (fused). No feature atomics.
__global__ __launch_bounds__(256) void k_argmin(const float* __restrict__ pos,
    const int* __restrict__ batch, int N, const float4* __restrict__ cent4,
    const int* __restrict__ batchStartC, int* __restrict__ assign,
    int* __restrict__ chunkHist2){
  __shared__ float4 sc[MMAX];         // 16 KB
  __shared__ int h[MMAX];             // 4 KB
  for (int m = threadIdx.x; m < MMAX; m += 256){ sc[m] = cent4[m]; h[m] = 0; }
  __syncthreads();
  int c = blockIdx.x;
  int lo = c * CHUNK, hi = min(N, lo + CHUNK);
  for (int i = lo + threadIdx.x; i < hi; i += 256){
    float px = pos[3*i+0], py = pos[3*i+1], pz = pos[3*i+2];
    float p2 = __fadd_rn(__fadd_rn(__fmul_rn(px,px), __fmul_rn(py,py)), __fmul_rn(pz,pz));
    int b = batch[i];
    int mlo = batchStartC[b], mhi = batchStartC[b+1];
    float best = 3.402823466e+38f;
    int bm = mlo;
    for (int m = mlo; m < mhi; m++){
      float4 cc = sc[m];
      float dot = __fadd_rn(__fadd_rn(__fmul_rn(px,cc.x), __fmul_rn(py,cc.y)),
                            __fmul_rn(pz,cc.z));
      float d2  = __fadd_rn(__fsub_rn(p2, __fmul_rn(2.0f, dot)), cc.w);
      if (d2 < best){ best = d2; bm = m; }
    }
    assign[i] = bm;
    atomicAdd(&h[bm], 1);
  }
  __syncthreads();
  for (int t = threadIdx.x; t < MMAX; t += 256)
    chunkHist2[c * MMAX + t] = h[t];
}

// K6b: column prefix over cluster chunk-hists; emits per-cluster totals
__global__ __launch_bounds__(256) void k_colscan2(int nchunks,
    int* __restrict__ chunkHist2, int* __restrict__ clustCnt){
  int v = blockIdx.x * 256 + threadIdx.x;
  if (v >= MMAX) return;
  int run = 0;
  for (int c = 0; c < nchunks; c++){
    int t = chunkHist2[c * MMAX + v];
    chunkHist2[c * MMAX + v] = run;
    run += t;
  }
  clustCnt[v] = run;
}

// K6c: single-wave exclusive scan of cluster counts -> clustBase
__global__ __launch_bounds__(64) void k_cbase(const int* __restrict__ clustCnt,
    int* __restrict__ clustBase){
  int lane = threadIdx.x;
  int cs[16]; int tot = 0;
  #pragma unroll
  for (int j = 0; j < 16; j++){ cs[j] = clustCnt[lane*16 + j]; tot += cs[j]; }
  int inc = tot;
  #pragma unroll
  for (int off = 1; off < 64; off <<= 1){
    int t = __shfl_up(inc, off);
    if (lane >= off) inc += t;
  }
  int bb = inc - tot;
  #pragma unroll
  for (int j = 0; j < 16; j++){ clustBase[lane*16 + j] = bb; bb += cs[j]; }
}

// K6d: stable scatter of point INDICES by assigned cluster (wave per chunk)
__global__ __launch_bounds__(64) void k_scatter2(const int* __restrict__ assign,
    int N, const int* __restrict__ chunkHist2, const int* __restrict__ clustBase,
    int* __restrict__ idx_sorted){
  __shared__ int cur[MMAX];
  int c = blockIdx.x, lane = threadIdx.x;
  for (int t = lane; t < MMAX; t += 64) cur[t] = chunkHist2[c * MMAX + t] + clustBase[t];
  __syncthreads();
  int lo = c * CHUNK;
  for (int r = 0; r < CHUNK/64; r++){
    int i = lo + r*64 + lane;
    bool valid = i < N;
    int v = valid ? assign[i] : -1;
    int rank = 0, cnt = 0, leader = -1;
    #pragma unroll 8
    for (int j = 0; j < 64; j++){
      int vj = __shfl(v, j);
      if (vj == v){
        cnt++;
        if (j < lane) rank++;
        if (leader < 0) leader = j;
      }
    }
    int old = 0;
    if (valid && rank == 0) old = atomicAdd(&cur[v], cnt);
    int base = __shfl(old, leader);
    if (valid) idx_sorted[base + rank] = i;
  }
}

// K6e: per-cluster feature max. One wave per cluster, lane = feature.
//      Coalesced 256B row gathers; max is exact & order-independent.
//      Empty cluster (incl. padded slots) -> 0, matching isfinite->0.
__global__ __launch_bounds__(256) void k_xmax(const float* __restrict__ x,
    const int* __restrict__ idx_sorted, const int* __restrict__ clustBase,
    const int* __restrict__ clustCnt, float* __restrict__ outX){
  int w = blockIdx.x * 4 + (threadIdx.x >> 6);   // cluster id
  int lane = threadIdx.x & 63;                   // feature id
  if (w >= MMAX) return;
  int lo = clustBase[w], cnt = clustCnt[w];
  float mx = -3.402823466e+38f;
  int k = 0;
  for (; k + 2 <= cnt; k += 2){
    int r0 = idx_sorted[lo+k], r1 = idx_sorted[lo+k+1];
    float a = x[(size_t)r0 * FDIM + lane];
    float b = x[(size_t)r1 * FDIM + lane];
    mx = fmaxf(mx, fmaxf(a, b));
  }
  if (k < cnt){
    int r0 = idx_sorted[lo+k];
    mx = fmaxf(mx, x[(size_t)r0 * FDIM + lane]);
  }
  outX[w * FDIM + lane] = (cnt > 0) ? mx : 0.0f;
}

// ---- fallback kernels (ws too small): atomic feature max + decode ----
__global__ __launch_bounds__(256) void k_assign_slow(const float* __restrict__ pos,
    const float* __restrict__ x, const int* __restrict__ batch, int N,
    const float4* __restrict__ cent4, const int* __restrict__ batchStartC,
    unsigned* __restrict__ encMax){
  __shared__ float4 sc[MMAX];
  for (int m = threadIdx.x; m < MMAX; m += blockDim.x) sc[m] = cent4[m];
  __syncthreads();
  int i = blockIdx.x * blockDim.x + threadIdx.x;
  if (i >= N) return;
  float px = pos[3*i+0], py = pos[3*i+1], pz = pos[3*i+2];
  float p2 = __fadd_rn(__fadd_rn(__fmul_rn(px,px), __fmul_rn(py,py)), __fmul_rn(pz,pz));
  int b = batch[i];
  int mlo = batchStartC[b], mhi = batchStartC[b+1];
  float best = 3.402823466e+38f;
  int bm = mlo;
  for (int m = mlo; m < mhi; m++){
    float4 c = sc[m];
    float dot = __fadd_rn(__fadd_rn(__fmul_rn(px,c.x), __fmul_rn(py,c.y)),
                          __fmul_rn(pz,c.z));
    float d2  = __fadd_rn(__fsub_rn(p2, __fmul_rn(2.0f, dot)), c.w);
    if (d2 < best){ best = d2; bm = m; }
  }
  unsigned* dst = encMax + bm * FDIM;
  const float4* xi = (const float4*)(x + (size_t)i * FDIM);
  #pragma unroll
  for (int f4 = 0; f4 < FDIM/4; f4++){
    float4 xv = xi[f4];
    atomicMax(&dst[4*f4+0], encf(xv.x));
    atomicMax(&dst[4*f4+1], encf(xv.y));
    atomicMax(&dst[4*f4+2], encf(xv.z));
    atomicMax(&dst[4*f4+3], encf(xv.w));
  }
}
__global__ __launch_bounds__(256) void k_decode(const unsigned* __restrict__ encMax,
    float* __restrict__ outX){
  int t = blockIdx.x * blockDim.x + threadIdx.x;
  if (t >= MMAX * FDIM) return;
  unsigned e = encMax[t];
  outX[t] = (e == 0u) ? 0.0f : decf(e);
}

// ---- workspace layout (bytes) ----
// 0      : startEnc      3 x u32   (memset 0xFF)
// 16     : batchCnt      4 x i32   (memset 0)
// 32     : batchPtr      5 x i32
// 64     : Mout          1 x i32
// 80     : batchStartC   5 x i32
// 128    : counts        2048 x i32
// 8320   : voxBase       2048 x i32
// 16512  : sum_pos       2048 x 3 x f32   [aliased after k_cent: clustCnt(1024) + clustBase(1024)]
// 41088  : idxOfCluster  1024 x i32
// 45184  : cent4         1024 x float4
// 61568  : encMax        1024 x 64 x u32  (fallback only)
// 323712 : vox           N x i32
// then   : chunkHist     nchunks x 2048 x i32  [aliased after k_scatter: chunkHist2 nchunks x 1024]
// then   : pos_sorted    N x 3 x f32           [aliased after k_sum2: assign(N) + idx_sorted(N)]

extern "C" void kernel_launch(void* const* d_in, const int* in_sizes, int n_in,
                              void* d_out, int out_size, void* d_ws, size_t ws_size,
                              hipStream_t stream){
  const float* pos   = (const float*)d_in[0];
  const float* x     = (const float*)d_in[1];
  const int*   batch = (const int*)d_in[2];
  const int N = in_sizes[2];
  const int nchunks = (N + CHUNK - 1) / CHUNK;

  char* w = (char*)d_ws;
  unsigned* startEnc     = (unsigned*)(w + 0);
  int*      batchCnt     = (int*)(w + 16);
  int*      batchPtr     = (int*)(w + 32);
  int*      Mout         = (int*)(w + 64);
  int*      batchStartC  = (int*)(w + 80);
  int*      counts       = (int*)(w + 128);
  int*      voxBase      = (int*)(w + 8320);
  float*    sum_pos      = (float*)(w + 16512);
  int*      idxOfCluster = (int*)(w + 41088);
  float4*   cent4        = (float4*)(w + 45184);
  unsigned* encMax       = (unsigned*)(w + 61568);
  int*      vox          = (int*)(w + 323712);
  size_t voxEnd = 323712 + (size_t)N * 4;
  size_t chOff  = (voxEnd + 15) & ~(size_t)15;
  int*      chunkHist    = (int*)(w + chOff);
  size_t psOff  = chOff + (size_t)nchunks * NVOX * 4;
  float*    pos_sorted   = (float*)(w + psOff);
  size_t need = psOff + (size_t)N * 3 * 4;
  const bool fast = (ws_size >= need);

  // aliases (fast path only; all producer/consumer orderings are stream-serial)
  int* clustCnt   = (int*)sum_pos;            // after k_cent
  int* clustBase  = (int*)sum_pos + MMAX;     // after k_cent
  int* chunkHist2 = chunkHist;                // after k_scatter
  int* assign     = (int*)pos_sorted;         // after k_sum2
  int* idx_sorted = (int*)pos_sorted + N;     // after k_sum2

  float* outX     = (float*)d_out;          // [1024,64]
  float* outC     = outX + MMAX * FDIM;     // [1024,3]
  float* outNB    = outC + MMAX * 3;        // [1024]
  float* outValid = outNB + MMAX;           // [1024]

  hipMemsetAsync(startEnc, 0xFF, 12, stream);
  hipMemsetAsync(batchCnt, 0, 16, stream);

  const int nb = (N + 255) / 256;
  k_min_hist<<<256, 256, 0, stream>>>(pos, batch, N, startEnc, batchCnt);
  if (fast){
    k_vox2<<<nb, 256, 0, stream>>>(pos, batch, N, startEnc, vox);
    k_chist<<<nchunks, 256, 0, stream>>>(vox, N, chunkHist);
    k_colscan<<<NVOX / 256, 256, 0, stream>>>(nchunks, chunkHist, counts);
    k_scan<<<1, 64, 0, stream>>>(counts, batchCnt, batchPtr, Mout, batchStartC,
                                 idxOfCluster, voxBase);
    k_scatter<<<nchunks, 64, 0, stream>>>(pos, vox, N, chunkHist, voxBase, pos_sorted);
    k_sum2<<<NVOX / 256, 256, 0, stream>>>(pos_sorted, voxBase, counts, sum_pos);
    k_cent<<<(MMAX + 255) / 256, 256, 0, stream>>>(sum_pos, counts, idxOfCluster, Mout,
                                                   cent4, outC, outNB, outValid);
    k_argmin<<<nchunks, 256, 0, stream>>>(pos, batch, N, cent4, batchStartC,
                                          assign, chunkHist2);
    k_colscan2<<<MMAX / 256, 256, 0, stream>>>(nchunks, chunkHist2, clustCnt);
    k_cbase<<<1, 64, 0, stream>>>(clustCnt, clustBase);
    k_scatter2<<<nchunks, 64, 0, stream>>>(assign, N, chunkHist2, clustBase, idx_sorted);
    k_xmax<<<MMAX / 4, 256, 0, stream>>>(x, idx_sorted, clustBase, clustCnt, outX);
  } else {
    hipMemsetAsync(counts, 0, NVOX * 4, stream);
    hipMemsetAsync(encMax, 0, MMAX * FDIM * 4, stream);
    k_vox<<<nb, 256, 0, stream>>>(pos, batch, N, startEnc, vox, counts);
    k_scan<<<1, 64, 0, stream>>>(counts, batchCnt, batchPtr, Mout, batchStartC,
                                 idxOfCluster, voxBase);
    k_sum<<<(NVOX + 63) / 64, 64, 0, stream>>>(pos, vox, counts, batchPtr, sum_pos);
    k_cent<<<(MMAX + 255) / 256, 256, 0, stream>>>(sum_pos, counts, idxOfCluster, Mout,
                                                   cent4, outC, outNB, outValid);
    k_assign_slow<<<nb, 256, 0, stream>>>(pos, x, batch, N, cent4, batchStartC, encMax);
    k_decode<<<(MMAX * FDIM + 255) / 256, 256, 0, stream>>>(encMax, outX);
  }
}

// Round 6
// 299.579 us; speedup vs baseline: 11.0220x; 1.2774x over previous
//
#include <hip/hip_runtime.h>
#include <stdint.h>

#define DGRID 8
#define NVOX  2048      // B * D^3
#define NBATCH 4
#define MMAX  1024
#define FDIM  64

// ---- float <-> order-preserving unsigned encoding (for atomic min/max) ----
__device__ __forceinline__ unsigned encf(float f){
  unsigned u = __float_as_uint(f);
  return (u & 0x80000000u) ? ~u : (u | 0x80000000u);
}
__device__ __forceinline__ float decf(unsigned e){
  unsigned u = (e & 0x80000000u) ? (e ^ 0x80000000u) : ~e;
  return __uint_as_float(u);
}

// K1: global per-dim min of pos (encoded atomicMin) + batch histogram
__global__ __launch_bounds__(256) void k_min_hist(const float* __restrict__ pos,
    const int* __restrict__ batch, int N, unsigned* startEnc, int* batchCnt){
  __shared__ int sbin[NBATCH];
  if (threadIdx.x < NBATCH) sbin[threadIdx.x] = 0;
  __syncthreads();
  unsigned m0 = 0xFFFFFFFFu, m1 = 0xFFFFFFFFu, m2 = 0xFFFFFFFFu;
  int stride = gridDim.x * blockDim.x;
  for (int i = blockIdx.x * blockDim.x + threadIdx.x; i < N; i += stride){
    unsigned e0 = encf(pos[3*i+0]); if (e0 < m0) m0 = e0;
    unsigned e1 = encf(pos[3*i+1]); if (e1 < m1) m1 = e1;
    unsigned e2 = encf(pos[3*i+2]); if (e2 < m2) m2 = e2;
    atomicAdd(&sbin[batch[i]], 1);
  }
  #pragma unroll
  for (int off = 32; off > 0; off >>= 1){
    unsigned t0 = __shfl_down(m0, off); if (t0 < m0) m0 = t0;
    unsigned t1 = __shfl_down(m1, off); if (t1 < m1) m1 = t1;
    unsigned t2 = __shfl_down(m2, off); if (t2 < m2) m2 = t2;
  }
  if ((threadIdx.x & 63) == 0){
    atomicMin(&startEnc[0], m0);
    atomicMin(&startEnc[1], m1);
    atomicMin(&startEnc[2], m2);
  }
  __syncthreads();
  if (threadIdx.x < NBATCH) atomicAdd(&batchCnt[threadIdx.x], sbin[threadIdx.x]);
}

// common fp32 voxel-coord computation (bitwise np-fp32 emulation)
__device__ __forceinline__ int voxel_of(const float* pos, int i, int b,
                                        const unsigned* startEnc){
  float s0 = __fsub_rn(decf(startEnc[0]), 0.1f);
  float s1 = __fsub_rn(decf(startEnc[1]), 0.1f);
  float s2 = __fsub_rn(decf(startEnc[2]), 0.1f);
  float q0 = __fdiv_rn(__fsub_rn(pos[3*i+0], s0), 0.2f);
  float q1 = __fdiv_rn(__fsub_rn(pos[3*i+1], s1), 0.2f);
  float q2 = __fdiv_rn(__fsub_rn(pos[3*i+2], s2), 0.2f);
  int c0 = (int)floorf(q0); c0 = c0 < 0 ? 0 : (c0 > DGRID-1 ? DGRID-1 : c0);
  int c1 = (int)floorf(q1); c1 = c1 < 0 ? 0 : (c1 > DGRID-1 ? DGRID-1 : c1);
  int c2 = (int)floorf(q2); c2 = c2 < 0 ? 0 : (c2 > DGRID-1 ? DGRID-1 : c2);
  return ((b*DGRID + c0)*DGRID + c1)*DGRID + c2;
}

// K2-fast: voxel id per point + fused per-chunk LDS histogram
__global__ __launch_bounds__(256) void k_vox_hist(const float* __restrict__ pos,
    const int* __restrict__ batch, int N, const unsigned* __restrict__ startEnc,
    int chunkP, int* __restrict__ vox, int* __restrict__ chunkHist){
  __shared__ int h[NVOX];
  for (int t = threadIdx.x; t < NVOX; t += 256) h[t] = 0;
  __syncthreads();
  int c = blockIdx.x;
  int lo = c * chunkP, hi = min(N, lo + chunkP);
  for (int i = lo + threadIdx.x; i < hi; i += 256){
    int v = voxel_of(pos, i, batch[i], startEnc);
    vox[i] = v;
    atomicAdd(&h[v], 1);
  }
  __syncthreads();
  for (int t = threadIdx.x; t < NVOX; t += 256)
    chunkHist[c * NVOX + t] = h[t];
}

// K2-slow fallback: voxel id + atomic counts
__global__ __launch_bounds__(256) void k_vox(const float* __restrict__ pos,
    const int* __restrict__ batch, int N, const unsigned* __restrict__ startEnc,
    int* __restrict__ vox, int* __restrict__ counts){
  int i = blockIdx.x * blockDim.x + threadIdx.x;
  if (i >= N) return;
  int v = voxel_of(pos, i, batch[i], startEnc);
  vox[i] = v;
  atomicAdd(&counts[v], 1);
}

// K2c: in-place exclusive column prefix over chunks; emits total -> counts[v]
__global__ __launch_bounds__(256) void k_colscan(int nchunks,
    int* __restrict__ chunkHist, int* __restrict__ counts){
  int v = blockIdx.x * 256 + threadIdx.x;
  if (v >= NVOX) return;
  int run = 0;
  for (int c = 0; c < nchunks; c++){
    int t = chunkHist[c * NVOX + v];
    chunkHist[c * NVOX + v] = run;
    run += t;
  }
  counts[v] = run;
}

// K3: single-wave scans: nonempty compaction, per-batch ranges, AND
//     exclusive prefix sum of counts -> voxBase (for counting sort).
__global__ __launch_bounds__(64) void k_scan(const int* __restrict__ counts,
    const int* __restrict__ batchCnt, int* batchPtr, int* Mout,
    int* batchStartC, int* __restrict__ idxOfCluster, int* __restrict__ voxBase){
  int lane = threadIdx.x;          // one wave (64)
  int cs[32];
  int ne = 0, tot = 0;
  #pragma unroll
  for (int j = 0; j < 32; j++){
    int c = counts[lane*32 + j];
    cs[j] = c;
    ne += (c > 0) ? 1 : 0;
    tot += c;
  }
  int inc = ne, incT = tot;
  #pragma unroll
  for (int off = 1; off < 64; off <<= 1){
    int t  = __shfl_up(inc,  off);
    int tt = __shfl_up(incT, off);
    if (lane >= off){ inc += t; incT += tt; }
  }
  int exne = inc - ne;             // exclusive scan of nonempty counts
  int bb   = incT - tot;           // exclusive scan of total counts
  __shared__ int laneEx[64];
  __shared__ int sM;
  laneEx[lane] = exne;
  int run = exne;
  #pragma unroll
  for (int j = 0; j < 32; j++){
    voxBase[lane*32 + j] = bb;
    bb += cs[j];
    if (cs[j] > 0){
      if (run < MMAX) idxOfCluster[run] = lane*32 + j;
      run++;
    }
  }
  if (lane == 63) sM = run;
  __syncthreads();
  int M = sM;
  for (int m = M + lane; m < MMAX; m += 64) idxOfCluster[m] = 0;  // fill_value=0
  if (lane == 0){
    Mout[0] = M;
    int acc = 0;
    for (int b = 0; b < NBATCH; b++){ batchPtr[b] = acc; acc += batchCnt[b]; }
    batchPtr[NBATCH] = acc;
    for (int b = 0; b < NBATCH; b++) batchStartC[b] = laneEx[b*16]; // voxel b*512 boundary
    batchStartC[NBATCH] = (M < MMAX) ? M : MMAX;
  }
}

// K3c: stable scatter of pos into voxel-sorted order. One wave per chunk;
//      in-wave stable rank via shfl match loop; LDS per-voxel cursors.
__global__ __launch_bounds__(64) void k_scatter(const float* __restrict__ pos,
    const int* __restrict__ vox, int N, const int* __restrict__ chunkHist,
    const int* __restrict__ voxBase, int chunkP, float* __restrict__ pos_sorted){
  __shared__ int cur[NVOX];
  int c = blockIdx.x, lane = threadIdx.x;
  for (int t = lane; t < NVOX; t += 64) cur[t] = chunkHist[c * NVOX + t] + voxBase[t];
  __syncthreads();
  int lo = c * chunkP;
  int rows = chunkP >> 6;
  for (int r = 0; r < rows; r++){
    int i = lo + r*64 + lane;
    bool valid = i < N;
    int v = valid ? vox[i] : -1;
    float px = 0.f, py = 0.f, pz = 0.f;
    if (valid){ px = pos[3*i+0]; py = pos[3*i+1]; pz = pos[3*i+2]; }
    int rank = 0, cnt = 0, leader = -1;
    #pragma unroll 8
    for (int j = 0; j < 64; j++){
      int vj = __shfl(v, j);
      if (vj == v){
        cnt++;
        if (j < lane) rank++;
        if (leader < 0) leader = j;
      }
    }
    int old = 0;
    if (valid && rank == 0) old = atomicAdd(&cur[v], cnt);
    int base = __shfl(old, leader);
    if (valid){
      int dst = base + rank;
      pos_sorted[3*dst+0] = px;
      pos_sorted[3*dst+1] = py;
      pos_sorted[3*dst+2] = pz;
    }
  }
}

// K4-fast: per-voxel fp32 sums over the voxel's contiguous sorted run.
// Stable sort preserves original index order within each voxel, so the
// sequential __fadd_rn chain is BITWISE identical to numpy's scatter-add.
__global__ __launch_bounds__(256) void k_sum2(const float* __restrict__ pos_sorted,
    const int* __restrict__ voxBase, const int* __restrict__ counts,
    float* __restrict__ sum_pos){
  int v = blockIdx.x * 256 + threadIdx.x;
  if (v >= NVOX) return;
  int lo = voxBase[v], cnt = counts[v];
  float sx = 0.f, sy = 0.f, sz = 0.f;
  for (int k = 0; k < cnt; k++){
    sx = __fadd_rn(sx, pos_sorted[3*(lo+k)+0]);
    sy = __fadd_rn(sy, pos_sorted[3*(lo+k)+1]);
    sz = __fadd_rn(sz, pos_sorted[3*(lo+k)+2]);
  }
  sum_pos[3*v+0] = sx;
  sum_pos[3*v+1] = sy;
  sum_pos[3*v+2] = sz;
}

// K4-slow fallback (ws too small): exact point-order scan per voxel
__global__ __launch_bounds__(64) void k_sum(const float* __restrict__ pos,
    const int* __restrict__ vox, const int* __restrict__ counts,
    const int* __restrict__ batchPtr, float* __restrict__ sum_pos){
  int v = blockIdx.x * 64 + threadIdx.x;
  if (v >= NVOX) return;
  int b = v >> 9;
  int lo = batchPtr[b], hi = batchPtr[b+1];
  float sx = 0.f, sy = 0.f, sz = 0.f;
  if (counts[v] > 0){
    for (int i = lo; i < hi; i++){
      if (vox[i] == v){
        sx = __fadd_rn(sx, pos[3*i+0]);
        sy = __fadd_rn(sy, pos[3*i+1]);
        sz = __fadd_rn(sz, pos[3*i+2]);
      }
    }
  }
  sum_pos[3*v+0] = sx;
  sum_pos[3*v+1] = sy;
  sum_pos[3*v+2] = sz;
}

// K5: fp32 centroids (+ |c|^2 via sequential non-FMA sum), new_batch, valid
__global__ __launch_bounds__(256) void k_cent(const float* __restrict__ sum_pos,
    const int* __restrict__ counts, const int* __restrict__ idxOfCluster,
    const int* __restrict__ Mout, float4* __restrict__ cent4,
    float* __restrict__ outC, float* __restrict__ outNB, float* __restrict__ outValid){
  int m = blockIdx.x * blockDim.x + threadIdx.x;
  if (m >= MMAX) return;
  int M = Mout[0];
  int v = idxOfCluster[m];
  float den = fmaxf((float)counts[v], 1.0f);
  float cx = __fdiv_rn(sum_pos[3*v+0], den);
  float cy = __fdiv_rn(sum_pos[3*v+1], den);
  float cz = __fdiv_rn(sum_pos[3*v+2], den);
  float c2 = __fadd_rn(__fadd_rn(__fmul_rn(cx,cx), __fmul_rn(cy,cy)), __fmul_rn(cz,cz));
  cent4[m] = make_float4(cx, cy, cz, c2);
  outC[3*m+0] = cx; outC[3*m+1] = cy; outC[3*m+2] = cz;
  outNB[m] = (float)(v >> 9);
  outValid[m] = (m < M) ? 1.0f : 0.0f;
}

// K6-fast: per-point argmin (EXACT fp32 code), one point per thread,
//          fused per-block LDS cluster histogram -> global clustCnt.
__global__ __launch_bounds__(256) void k_argmin2(const float* __restrict__ pos,
    const int* __restrict__ batch, int N, const float4* __restrict__ cent4,
    const int* __restrict__ batchStartC, int* __restrict__ assign,
    int* __restrict__ clustCnt){
  __shared__ float4 sc[MMAX];         // 16 KB
  __shared__ int h[MMAX];             // 4 KB
  for (int m = threadIdx.x; m < MMAX; m += 256){ sc[m] = cent4[m]; h[m] = 0; }
  __syncthreads();
  int i = blockIdx.x * 256 + threadIdx.x;
  if (i < N){
    float px = pos[3*i+0], py = pos[3*i+1], pz = pos[3*i+2];
    float p2 = __fadd_rn(__fadd_rn(__fmul_rn(px,px), __fmul_rn(py,py)), __fmul_rn(pz,pz));
    int b = batch[i];
    int mlo = batchStartC[b], mhi = batchStartC[b+1];
    float best = 3.402823466e+38f;
    int bm = mlo;
    for (int m = mlo; m < mhi; m++){
      float4 cc = sc[m];
      float dot = __fadd_rn(__fadd_rn(__fmul_rn(px,cc.x), __fmul_rn(py,cc.y)),
                            __fmul_rn(pz,cc.z));
      float d2  = __fadd_rn(__fsub_rn(p2, __fmul_rn(2.0f, dot)), cc.w);
      if (d2 < best){ best = d2; bm = m; }
    }
    assign[i] = bm;
    atomicAdd(&h[bm], 1);
  }
  __syncthreads();
  for (int t = threadIdx.x; t < MMAX; t += 256){
    int c = h[t];
    if (c > 0) atomicAdd(&clustCnt[t], c);
  }
}

// K6c: single-wave exclusive scan of cluster counts -> clustBase, cur
__global__ __launch_bounds__(64) void k_cbase2(const int* __restrict__ clustCnt,
    int* __restrict__ clustBase, int* __restrict__ cur){
  int lane = threadIdx.x;
  int cs[16]; int tot = 0;
  #pragma unroll
  for (int j = 0; j < 16; j++){ cs[j] = clustCnt[lane*16 + j]; tot += cs[j]; }
  int inc = tot;
  #pragma unroll
  for (int off = 1; off < 64; off <<= 1){
    int t = __shfl_up(inc, off);
    if (lane >= off) inc += t;
  }
  int bb = inc - tot;
  #pragma unroll
  for (int j = 0; j < 16; j++){
    clustBase[lane*16 + j] = bb;
    cur[lane*16 + j] = bb;
    bb += cs[j];
  }
}

// K6d: unordered index scatter by cluster (fmax is order-independent, so
//      within-cluster order is irrelevant for the final bitwise output).
__global__ __launch_bounds__(256) void k_scatter2s(const int* __restrict__ assign,
    int N, int* __restrict__ cur, int* __restrict__ idx_sorted){
  int i = blockIdx.x * 256 + threadIdx.x;
  if (i >= N) return;
  int m = assign[i];
  int p = atomicAdd(&cur[m], 1);
  idx_sorted[p] = i;
}

// K6e: per-cluster feature max. One wave per cluster, lane = feature.
//      Coalesced 256B row gathers; 4-deep MLP. Empty/padded cluster -> 0.
__global__ __launch_bounds__(256) void k_xmax(const float* __restrict__ x,
    const int* __restrict__ idx_sorted, const int* __restrict__ clustBase,
    const int* __restrict__ clustCnt, float* __restrict__ outX){
  int w = blockIdx.x * 4 + (threadIdx.x >> 6);   // cluster id
  int lane = threadIdx.x & 63;                   // feature id
  if (w >= MMAX) return;
  int lo = clustBase[w], cnt = clustCnt[w];
  float mx = -3.402823466e+38f;
  int k = 0;
  for (; k + 4 <= cnt; k += 4){
    int r0 = idx_sorted[lo+k+0], r1 = idx_sorted[lo+k+1];
    int r2 = idx_sorted[lo+k+2], r3 = idx_sorted[lo+k+3];
    float a = x[(size_t)r0 * FDIM + lane];
    float b = x[(size_t)r1 * FDIM + lane];
    float c = x[(size_t)r2 * FDIM + lane];
    float d = x[(size_t)r3 * FDIM + lane];
    mx = fmaxf(mx, fmaxf(fmaxf(a, b), fmaxf(c, d)));
  }
  for (; k < cnt; k++){
    int r0 = idx_sorted[lo+k];
    mx = fmaxf(mx, x[(size_t)r0 * FDIM + lane]);
  }
  outX[w * FDIM + lane] = (cnt > 0) ? mx : 0.0f;
}

// ---- fallback kernels (ws too small): atomic feature max + decode ----
__global__ __launch_bounds__(256) void k_assign_slow(const float* __restrict__ pos,
    const float* __restrict__ x, const int* __restrict__ batch, int N,
    const float4* __restrict__ cent4, const int* __restrict__ batchStartC,
    unsigned* __restrict__ encMax){
  __shared__ float4 sc[MMAX];
  for (int m = threadIdx.x; m < MMAX; m += blockDim.x) sc[m] = cent4[m];
  __syncthreads();
  int i = blockIdx.x * blockDim.x + threadIdx.x;
  if (i >= N) return;
  float px = pos[3*i+0], py = pos[3*i+1], pz = pos[3*i+2];
  float p2 = __fadd_rn(__fadd_rn(__fmul_rn(px,px), __fmul_rn(py,py)), __fmul_rn(pz,pz));
  int b = batch[i];
  int mlo = batchStartC[b], mhi = batchStartC[b+1];
  float best = 3.402823466e+38f;
  int bm = mlo;
  for (int m = mlo; m < mhi; m++){
    float4 c = sc[m];
    float dot = __fadd_rn(__fadd_rn(__fmul_rn(px,c.x), __fmul_rn(py,c.y)),
                          __fmul_rn(pz,c.z));
    float d2  = __fadd_rn(__fsub_rn(p2, __fmul_rn(2.0f, dot)), c.w);
    if (d2 < best){ best = d2; bm = m; }
  }
  unsigned* dst = encMax + bm * FDIM;
  const float4* xi = (const float4*)(x + (size_t)i * FDIM);
  #pragma unroll
  for (int f4 = 0; f4 < FDIM/4; f4++){
    float4 xv = xi[f4];
    atomicMax(&dst[4*f4+0], encf(xv.x));
    atomicMax(&dst[4*f4+1], encf(xv.y));
    atomicMax(&dst[4*f4+2], encf(xv.z));
    atomicMax(&dst[4*f4+3], encf(xv.w));
  }
}
__global__ __launch_bounds__(256) void k_decode(const unsigned* __restrict__ encMax,
    float* __restrict__ outX){
  int t = blockIdx.x * blockDim.x + threadIdx.x;
  if (t >= MMAX * FDIM) return;
  unsigned e = encMax[t];
  outX[t] = (e == 0u) ? 0.0f : decf(e);
}

// ---- workspace layout (bytes) ----
// 0      : startEnc      3 x u32   (memset 0xFF)
// 16     : batchCnt      4 x i32   (memset 0)
// 32     : batchPtr      5 x i32
// 64     : Mout          1 x i32
// 80     : batchStartC   5 x i32
// 128    : counts        2048 x i32
// 8320   : voxBase       2048 x i32
// 16512  : sum_pos       2048 x 3 x f32  [aliased after k_cent: clustCnt | clustBase | cur]
// 41088  : idxOfCluster  1024 x i32
// 45184  : cent4         1024 x float4
// 61568  : encMax        1024 x 64 x u32 (fallback only)
// 323712 : vox           N x i32
// then   : chunkHist     nchunksP x 2048 x i32
// then   : pos_sorted    N x 3 x f32     [aliased after k_sum2: assign(N) | idx_sorted(N)]

extern "C" void kernel_launch(void* const* d_in, const int* in_sizes, int n_in,
                              void* d_out, int out_size, void* d_ws, size_t ws_size,
                              hipStream_t stream){
  const float* pos   = (const float*)d_in[0];
  const float* x     = (const float*)d_in[1];
  const int*   batch = (const int*)d_in[2];
  const int N = in_sizes[2];

  char* w = (char*)d_ws;
  unsigned* startEnc     = (unsigned*)(w + 0);
  int*      batchCnt     = (int*)(w + 16);
  int*      batchPtr     = (int*)(w + 32);
  int*      Mout         = (int*)(w + 64);
  int*      batchStartC  = (int*)(w + 80);
  int*      counts       = (int*)(w + 128);
  int*      voxBase      = (int*)(w + 8320);
  float*    sum_pos      = (float*)(w + 16512);
  int*      idxOfCluster = (int*)(w + 41088);
  float4*   cent4        = (float4*)(w + 45184);
  unsigned* encMax       = (unsigned*)(w + 61568);
  int*      vox          = (int*)(w + 323712);
  size_t voxEnd = 323712 + (size_t)N * 4;
  size_t chOff  = (voxEnd + 15) & ~(size_t)15;

  // pick phase-1 sort chunk size based on available workspace
  int chunkP = 256;
  int nchunksP = (N + chunkP - 1) / chunkP;
  size_t psOff = chOff + (size_t)nchunksP * NVOX * 4;
  size_t need  = psOff + (size_t)N * 3 * 4;
  bool fast = true;
  if (ws_size < need){
    chunkP = 1024;
    nchunksP = (N + chunkP - 1) / chunkP;
    psOff = chOff + (size_t)nchunksP * NVOX * 4;
    need  = psOff + (size_t)N * 3 * 4;
    if (ws_size < need) fast = false;
  }
  int*   chunkHist  = (int*)(w + chOff);
  float* pos_sorted = (float*)(w + psOff);

  // aliases (fast path only; all orderings are stream-serial)
  int* clustCnt   = (int*)sum_pos;            // after k_cent
  int* clustBase  = (int*)sum_pos + MMAX;
  int* cur        = (int*)sum_pos + 2*MMAX;
  int* assign     = (int*)pos_sorted;         // after k_sum2
  int* idx_sorted = (int*)pos_sorted + N;

  float* outX     = (float*)d_out;          // [1024,64]
  float* outC     = outX + MMAX * FDIM;     // [1024,3]
  float* outNB    = outC + MMAX * 3;        // [1024]
  float* outValid = outNB + MMAX;           // [1024]

  hipMemsetAsync(startEnc, 0xFF, 12, stream);
  hipMemsetAsync(batchCnt, 0, 16, stream);

  const int nb  = (N + 255) / 256;
  k_min_hist<<<256, 256, 0, stream>>>(pos, batch, N, startEnc, batchCnt);
  if (fast){
    k_vox_hist<<<nchunksP, 256, 0, stream>>>(pos, batch, N, startEnc, chunkP,
                                             vox, chunkHist);
    k_colscan<<<NVOX / 256, 256, 0, stream>>>(nchunksP, chunkHist, counts);
    k_scan<<<1, 64, 0, stream>>>(counts, batchCnt, batchPtr, Mout, batchStartC,
                                 idxOfCluster, voxBase);
    k_scatter<<<nchunksP, 64, 0, stream>>>(pos, vox, N, chunkHist, voxBase,
                                           chunkP, pos_sorted);
    k_sum2<<<NVOX / 256, 256, 0, stream>>>(pos_sorted, voxBase, counts, sum_pos);
    k_cent<<<(MMAX + 255) / 256, 256, 0, stream>>>(sum_pos, counts, idxOfCluster, Mout,
                                                   cent4, outC, outNB, outValid);
    hipMemsetAsync(clustCnt, 0, MMAX * 4, stream);   // after k_cent (aliases sum_pos)
    k_argmin2<<<nb, 256, 0, stream>>>(pos, batch, N, cent4, batchStartC,
                                      assign, clustCnt);
    k_cbase2<<<1, 64, 0, stream>>>(clustCnt, clustBase, cur);
    k_scatter2s<<<nb, 256, 0, stream>>>(assign, N, cur, idx_sorted);
    k_xmax<<<MMAX / 4, 256, 0, stream>>>(x, idx_sorted, clustBase, clustCnt, outX);
  } else {
    hipMemsetAsync(counts, 0, NVOX * 4, stream);
    hipMemsetAsync(encMax, 0, MMAX * FDIM * 4, stream);
    k_vox<<<nb, 256, 0, stream>>>(pos, batch, N, startEnc, vox, counts);
    k_scan<<<1, 64, 0, stream>>>(counts, batchCnt, batchPtr, Mout, batchStartC,
                                 idxOfCluster, voxBase);
    k_sum<<<(NVOX + 63) / 64, 64, 0, stream>>>(pos, vox, counts, batchPtr, sum_pos);
    k_cent<<<(MMAX + 255) / 256, 256, 0, stream>>>(sum_pos, counts, idxOfCluster, Mout,
                                                   cent4, outC, outNB, outValid);
    k_assign_slow<<<nb, 256, 0, stream>>>(pos, x, batch, N, cent4, batchStartC, encMax);
    k_decode<<<(MMAX * FDIM + 255) / 256, 256, 0, stream>>>(encMax, outX);
  }
}

// Round 7
// 179.153 us; speedup vs baseline: 18.4309x; 1.6722x over previous
//
#include <hip/hip_runtime.h>
#include <stdint.h>

#define DGRID 8
#define NVOX  2048      // B * D^3
#define NBATCH 4
#define MMAX  1024
#define FDIM  64
#define GRP   20        // chunks per scan group (ngroups <= 32 fits gsum in encMax)

// ---- float <-> order-preserving unsigned encoding (for atomic min/max) ----
__device__ __forceinline__ unsigned encf(float f){
  unsigned u = __float_as_uint(f);
  return (u & 0x80000000u) ? ~u : (u | 0x80000000u);
}
__device__ __forceinline__ float decf(unsigned e){
  unsigned u = (e & 0x80000000u) ? (e ^ 0x80000000u) : ~e;
  return __uint_as_float(u);
}

// K1: global per-dim min of pos (encoded atomicMin) + batch histogram
__global__ __launch_bounds__(256) void k_min_hist(const float* __restrict__ pos,
    const int* __restrict__ batch, int N, unsigned* startEnc, int* batchCnt){
  __shared__ int sbin[NBATCH];
  if (threadIdx.x < NBATCH) sbin[threadIdx.x] = 0;
  __syncthreads();
  unsigned m0 = 0xFFFFFFFFu, m1 = 0xFFFFFFFFu, m2 = 0xFFFFFFFFu;
  int stride = gridDim.x * blockDim.x;
  for (int i = blockIdx.x * blockDim.x + threadIdx.x; i < N; i += stride){
    unsigned e0 = encf(pos[3*i+0]); if (e0 < m0) m0 = e0;
    unsigned e1 = encf(pos[3*i+1]); if (e1 < m1) m1 = e1;
    unsigned e2 = encf(pos[3*i+2]); if (e2 < m2) m2 = e2;
    atomicAdd(&sbin[batch[i]], 1);
  }
  #pragma unroll
  for (int off = 32; off > 0; off >>= 1){
    unsigned t0 = __shfl_down(m0, off); if (t0 < m0) m0 = t0;
    unsigned t1 = __shfl_down(m1, off); if (t1 < m1) m1 = t1;
    unsigned t2 = __shfl_down(m2, off); if (t2 < m2) m2 = t2;
  }
  if ((threadIdx.x & 63) == 0){
    atomicMin(&startEnc[0], m0);
    atomicMin(&startEnc[1], m1);
    atomicMin(&startEnc[2], m2);
  }
  __syncthreads();
  if (threadIdx.x < NBATCH) atomicAdd(&batchCnt[threadIdx.x], sbin[threadIdx.x]);
}

// common fp32 voxel-coord computation (bitwise np-fp32 emulation)
__device__ __forceinline__ int voxel_of(const float* pos, int i, int b,
                                        const unsigned* startEnc){
  float s0 = __fsub_rn(decf(startEnc[0]), 0.1f);
  float s1 = __fsub_rn(decf(startEnc[1]), 0.1f);
  float s2 = __fsub_rn(decf(startEnc[2]), 0.1f);
  float q0 = __fdiv_rn(__fsub_rn(pos[3*i+0], s0), 0.2f);
  float q1 = __fdiv_rn(__fsub_rn(pos[3*i+1], s1), 0.2f);
  float q2 = __fdiv_rn(__fsub_rn(pos[3*i+2], s2), 0.2f);
  int c0 = (int)floorf(q0); c0 = c0 < 0 ? 0 : (c0 > DGRID-1 ? DGRID-1 : c0);
  int c1 = (int)floorf(q1); c1 = c1 < 0 ? 0 : (c1 > DGRID-1 ? DGRID-1 : c1);
  int c2 = (int)floorf(q2); c2 = c2 < 0 ? 0 : (c2 > DGRID-1 ? DGRID-1 : c2);
  return ((b*DGRID + c0)*DGRID + c1)*DGRID + c2;
}

// K2-fast: voxel id per point + fused per-chunk LDS histogram
__global__ __launch_bounds__(256) void k_vox_hist(const float* __restrict__ pos,
    const int* __restrict__ batch, int N, const unsigned* __restrict__ startEnc,
    int chunkP, int* __restrict__ vox, int* __restrict__ chunkHist){
  __shared__ int h[NVOX];
  for (int t = threadIdx.x; t < NVOX; t += 256) h[t] = 0;
  __syncthreads();
  int c = blockIdx.x;
  int lo = c * chunkP, hi = min(N, lo + chunkP);
  for (int i = lo + threadIdx.x; i < hi; i += 256){
    int v = voxel_of(pos, i, batch[i], startEnc);
    vox[i] = v;
    atomicAdd(&h[v], 1);
  }
  __syncthreads();
  for (int t = threadIdx.x; t < NVOX; t += 256)
    chunkHist[c * NVOX + t] = h[t];
}

// K2-slow fallback: voxel id + atomic counts
__global__ __launch_bounds__(256) void k_vox(const float* __restrict__ pos,
    const int* __restrict__ batch, int N, const unsigned* __restrict__ startEnc,
    int* __restrict__ vox, int* __restrict__ counts){
  int i = blockIdx.x * blockDim.x + threadIdx.x;
  if (i >= N) return;
  int v = voxel_of(pos, i, batch[i], startEnc);
  vox[i] = v;
  atomicAdd(&counts[v], 1);
}

// K2c-a: per-group partial sums over chunks (coalesced along v)
__global__ __launch_bounds__(256) void k_gsum(int nchunks, int ngroups,
    const int* __restrict__ chunkHist, int* __restrict__ gsum){
  int g = blockIdx.x >> 3;
  int v = (blockIdx.x & 7) * 256 + threadIdx.x;
  if (g >= ngroups) return;
  int c0 = g * GRP, c1 = min(nchunks, c0 + GRP);
  int s = 0;
  for (int c = c0; c < c1; c++) s += chunkHist[c * NVOX + v];
  gsum[g * NVOX + v] = s;
}

// K2c-b: exclusive scan of group sums per voxel (serial ngroups<=32) -> counts
__global__ __launch_bounds__(256) void k_gscan(int ngroups,
    int* __restrict__ gsum, int* __restrict__ counts){
  int v = blockIdx.x * 256 + threadIdx.x;
  if (v >= NVOX) return;
  int run = 0;
  for (int g = 0; g < ngroups; g++){
    int t = gsum[g * NVOX + v];
    gsum[g * NVOX + v] = run;
    run += t;
  }
  counts[v] = run;
}

// K2c-c: within-group exclusive scan write-back (global chunk bases)
__global__ __launch_bounds__(256) void k_colwrite(int nchunks, int ngroups,
    int* __restrict__ chunkHist, const int* __restrict__ gsum){
  int g = blockIdx.x >> 3;
  int v = (blockIdx.x & 7) * 256 + threadIdx.x;
  if (g >= ngroups) return;
  int run = gsum[g * NVOX + v];
  int c0 = g * GRP, c1 = min(nchunks, c0 + GRP);
  for (int c = c0; c < c1; c++){
    int t = chunkHist[c * NVOX + v];
    chunkHist[c * NVOX + v] = run;
    run += t;
  }
}

// K3: single-wave scans: nonempty compaction, per-batch ranges, AND
//     exclusive prefix sum of counts -> voxBase (for counting sort).
__global__ __launch_bounds__(64) void k_scan(const int* __restrict__ counts,
    const int* __restrict__ batchCnt, int* batchPtr, int* Mout,
    int* batchStartC, int* __restrict__ idxOfCluster, int* __restrict__ voxBase){
  int lane = threadIdx.x;          // one wave (64)
  int cs[32];
  int ne = 0, tot = 0;
  #pragma unroll
  for (int j = 0; j < 32; j++){
    int c = counts[lane*32 + j];
    cs[j] = c;
    ne += (c > 0) ? 1 : 0;
    tot += c;
  }
  int inc = ne, incT = tot;
  #pragma unroll
  for (int off = 1; off < 64; off <<= 1){
    int t  = __shfl_up(inc,  off);
    int tt = __shfl_up(incT, off);
    if (lane >= off){ inc += t; incT += tt; }
  }
  int exne = inc - ne;             // exclusive scan of nonempty counts
  int bb   = incT - tot;           // exclusive scan of total counts
  __shared__ int laneEx[64];
  __shared__ int sM;
  laneEx[lane] = exne;
  int run = exne;
  #pragma unroll
  for (int j = 0; j < 32; j++){
    voxBase[lane*32 + j] = bb;
    bb += cs[j];
    if (cs[j] > 0){
      if (run < MMAX) idxOfCluster[run] = lane*32 + j;
      run++;
    }
  }
  if (lane == 63) sM = run;
  __syncthreads();
  int M = sM;
  for (int m = M + lane; m < MMAX; m += 64) idxOfCluster[m] = 0;  // fill_value=0
  if (lane == 0){
    Mout[0] = M;
    int acc = 0;
    for (int b = 0; b < NBATCH; b++){ batchPtr[b] = acc; acc += batchCnt[b]; }
    batchPtr[NBATCH] = acc;
    for (int b = 0; b < NBATCH; b++) batchStartC[b] = laneEx[b*16]; // voxel b*512 boundary
    batchStartC[NBATCH] = (M < MMAX) ? M : MMAX;
  }
}

// K3c: stable scatter of pos into voxel-sorted order. One wave per chunk;
//      in-wave stable rank via shfl match loop; LDS per-voxel cursors.
__global__ __launch_bounds__(64) void k_scatter(const float* __restrict__ pos,
    const int* __restrict__ vox, int N, const int* __restrict__ chunkHist,
    const int* __restrict__ voxBase, int chunkP, float* __restrict__ pos_sorted){
  __shared__ int cur[NVOX];
  int c = blockIdx.x, lane = threadIdx.x;
  for (int t = lane; t < NVOX; t += 64) cur[t] = chunkHist[c * NVOX + t] + voxBase[t];
  __syncthreads();
  int lo = c * chunkP;
  int rows = chunkP >> 6;
  for (int r = 0; r < rows; r++){
    int i = lo + r*64 + lane;
    bool valid = i < N;
    int v = valid ? vox[i] : -1;
    float px = 0.f, py = 0.f, pz = 0.f;
    if (valid){ px = pos[3*i+0]; py = pos[3*i+1]; pz = pos[3*i+2]; }
    int rank = 0, cnt = 0, leader = -1;
    #pragma unroll 8
    for (int j = 0; j < 64; j++){
      int vj = __shfl(v, j);
      if (vj == v){
        cnt++;
        if (j < lane) rank++;
        if (leader < 0) leader = j;
      }
    }
    int old = 0;
    if (valid && rank == 0) old = atomicAdd(&cur[v], cnt);
    int base = __shfl(old, leader);
    if (valid){
      int dst = base + rank;
      pos_sorted[3*dst+0] = px;
      pos_sorted[3*dst+1] = py;
      pos_sorted[3*dst+2] = pz;
    }
  }
}

// K4-fast: per-voxel fp32 sums over the voxel's contiguous sorted run.
// 4-deep load batching for MLP; the __fadd_rn chain order is untouched,
// so the result is BITWISE identical to numpy's sequential scatter-add.
__global__ __launch_bounds__(64) void k_sum2(const float* __restrict__ pos_sorted,
    const int* __restrict__ voxBase, const int* __restrict__ counts,
    float* __restrict__ sum_pos){
  int v = blockIdx.x * 64 + threadIdx.x;
  if (v >= NVOX) return;
  int lo = voxBase[v], cnt = counts[v];
  const float* p = pos_sorted + 3*(size_t)lo;
  float sx = 0.f, sy = 0.f, sz = 0.f;
  int k = 0;
  for (; k + 4 <= cnt; k += 4){
    float a0 = p[12*0+0], a1 = p[12*0+1], a2 = p[12*0+2];
    float b0 = p[3+0],    b1 = p[3+1],    b2 = p[3+2];
    float c0 = p[6+0],    c1 = p[6+1],    c2 = p[6+2];
    float d0 = p[9+0],    d1 = p[9+1],    d2 = p[9+2];
    sx = __fadd_rn(__fadd_rn(__fadd_rn(__fadd_rn(sx, a0), b0), c0), d0);
    sy = __fadd_rn(__fadd_rn(__fadd_rn(__fadd_rn(sy, a1), b1), c1), d1);
    sz = __fadd_rn(__fadd_rn(__fadd_rn(__fadd_rn(sz, a2), b2), c2), d2);
    p += 12;
  }
  for (; k < cnt; k++){
    sx = __fadd_rn(sx, p[0]);
    sy = __fadd_rn(sy, p[1]);
    sz = __fadd_rn(sz, p[2]);
    p += 3;
  }
  sum_pos[3*v+0] = sx;
  sum_pos[3*v+1] = sy;
  sum_pos[3*v+2] = sz;
}

// K4-slow fallback (ws too small): exact point-order scan per voxel
__global__ __launch_bounds__(64) void k_sum(const float* __restrict__ pos,
    const int* __restrict__ vox, const int* __restrict__ counts,
    const int* __restrict__ batchPtr, float* __restrict__ sum_pos){
  int v = blockIdx.x * 64 + threadIdx.x;
  if (v >= NVOX) return;
  int b = v >> 9;
  int lo = batchPtr[b], hi = batchPtr[b+1];
  float sx = 0.f, sy = 0.f, sz = 0.f;
  if (counts[v] > 0){
    for (int i = lo; i < hi; i++){
      if (vox[i] == v){
        sx = __fadd_rn(sx, pos[3*i+0]);
        sy = __fadd_rn(sy, pos[3*i+1]);
        sz = __fadd_rn(sz, pos[3*i+2]);
      }
    }
  }
  sum_pos[3*v+0] = sx;
  sum_pos[3*v+1] = sy;
  sum_pos[3*v+2] = sz;
}

// K5: fp32 centroids (+ |c|^2 via sequential non-FMA sum), new_batch, valid
__global__ __launch_bounds__(256) void k_cent(const float* __restrict__ sum_pos,
    const int* __restrict__ counts, const int* __restrict__ idxOfCluster,
    const int* __restrict__ Mout, float4* __restrict__ cent4,
    float* __restrict__ outC, float* __restrict__ outNB, float* __restrict__ outValid){
  int m = blockIdx.x * blockDim.x + threadIdx.x;
  if (m >= MMAX) return;
  int M = Mout[0];
  int v = idxOfCluster[m];
  float den = fmaxf((float)counts[v], 1.0f);
  float cx = __fdiv_rn(sum_pos[3*v+0], den);
  float cy = __fdiv_rn(sum_pos[3*v+1], den);
  float cz = __fdiv_rn(sum_pos[3*v+2], den);
  float c2 = __fadd_rn(__fadd_rn(__fmul_rn(cx,cx), __fmul_rn(cy,cy)), __fmul_rn(cz,cz));
  cent4[m] = make_float4(cx, cy, cz, c2);
  outC[3*m+0] = cx; outC[3*m+1] = cy; outC[3*m+2] = cz;
  outNB[m] = (float)(v >> 9);
  outValid[m] = (m < M) ? 1.0f : 0.0f;
}

// K6-fast: per-point argmin (EXACT fp32 code), one point per thread,
//          fused per-block LDS cluster histogram -> global clustCnt.
__global__ __launch_bounds__(256) void k_argmin2(const float* __restrict__ pos,
    const int* __restrict__ batch, int N, const float4* __restrict__ cent4,
    const int* __restrict__ batchStartC, int* __restrict__ assign,
    int* __restrict__ clustCnt){
  __shared__ float4 sc[MMAX];         // 16 KB
  __shared__ int h[MMAX];             // 4 KB
  for (int m = threadIdx.x; m < MMAX; m += 256){ sc[m] = cent4[m]; h[m] = 0; }
  __syncthreads();
  int i = blockIdx.x * 256 + threadIdx.x;
  if (i < N){
    float px = pos[3*i+0], py = pos[3*i+1], pz = pos[3*i+2];
    float p2 = __fadd_rn(__fadd_rn(__fmul_rn(px,px), __fmul_rn(py,py)), __fmul_rn(pz,pz));
    int b = batch[i];
    int mlo = batchStartC[b], mhi = batchStartC[b+1];
    float best = 3.402823466e+38f;
    int bm = mlo;
    for (int m = mlo; m < mhi; m++){
      float4 cc = sc[m];
      float dot = __fadd_rn(__fadd_rn(__fmul_rn(px,cc.x), __fmul_rn(py,cc.y)),
                            __fmul_rn(pz,cc.z));
      float d2  = __fadd_rn(__fsub_rn(p2, __fmul_rn(2.0f, dot)), cc.w);
      if (d2 < best){ best = d2; bm = m; }
    }
    assign[i] = bm;
    atomicAdd(&h[bm], 1);
  }
  __syncthreads();
  for (int t = threadIdx.x; t < MMAX; t += 256){
    int c = h[t];
    if (c > 0) atomicAdd(&clustCnt[t], c);
  }
}

// K6c: single-wave exclusive scan of cluster counts -> clustBase, cur
__global__ __launch_bounds__(64) void k_cbase2(const int* __restrict__ clustCnt,
    int* __restrict__ clustBase, int* __restrict__ cur){
  int lane = threadIdx.x;
  int cs[16]; int tot = 0;
  #pragma unroll
  for (int j = 0; j < 16; j++){ cs[j] = clustCnt[lane*16 + j]; tot += cs[j]; }
  int inc = tot;
  #pragma unroll
  for (int off = 1; off < 64; off <<= 1){
    int t = __shfl_up(inc, off);
    if (lane >= off) inc += t;
  }
  int bb = inc - tot;
  #pragma unroll
  for (int j = 0; j < 16; j++){
    clustBase[lane*16 + j] = bb;
    cur[lane*16 + j] = bb;
    bb += cs[j];
  }
}

// K6d: unordered index scatter by cluster (fmax is order-independent, so
//      within-cluster order is irrelevant for the final bitwise output).
__global__ __launch_bounds__(256) void k_scatter2s(const int* __restrict__ assign,
    int N, int* __restrict__ cur, int* __restrict__ idx_sorted){
  int i = blockIdx.x * 256 + threadIdx.x;
  if (i >= N) return;
  int m = assign[i];
  int p = atomicAdd(&cur[m], 1);
  idx_sorted[p] = i;
}

// K6e: per-cluster feature max. One wave per cluster, lane = feature.
//      Coalesced 256B row gathers; 4-deep MLP. Empty/padded cluster -> 0.
__global__ __launch_bounds__(256) void k_xmax(const float* __restrict__ x,
    const int* __restrict__ idx_sorted, const int* __restrict__ clustBase,
    const int* __restrict__ clustCnt, float* __restrict__ outX){
  int w = blockIdx.x * 4 + (threadIdx.x >> 6);   // cluster id
  int lane = threadIdx.x & 63;                   // feature id
  if (w >= MMAX) return;
  int lo = clustBase[w], cnt = clustCnt[w];
  float mx = -3.402823466e+38f;
  int k = 0;
  for (; k + 4 <= cnt; k += 4){
    int r0 = idx_sorted[lo+k+0], r1 = idx_sorted[lo+k+1];
    int r2 = idx_sorted[lo+k+2], r3 = idx_sorted[lo+k+3];
    float a = x[(size_t)r0 * FDIM + lane];
    float b = x[(size_t)r1 * FDIM + lane];
    float c = x[(size_t)r2 * FDIM + lane];
    float d = x[(size_t)r3 * FDIM + lane];
    mx = fmaxf(mx, fmaxf(fmaxf(a, b), fmaxf(c, d)));
  }
  for (; k < cnt; k++){
    int r0 = idx_sorted[lo+k];
    mx = fmaxf(mx, x[(size_t)r0 * FDIM + lane]);
  }
  outX[w * FDIM + lane] = (cnt > 0) ? mx : 0.0f;
}

// ---- fallback kernels (ws too small): atomic feature max + decode ----
__global__ __launch_bounds__(256) void k_assign_slow(const float* __restrict__ pos,
    const float* __restrict__ x, const int* __restrict__ batch, int N,
    const float4* __restrict__ cent4, const int* __restrict__ batchStartC,
    unsigned* __restrict__ encMax){
  __shared__ float4 sc[MMAX];
  for (int m = threadIdx.x; m < MMAX; m += blockDim.x) sc[m] = cent4[m];
  __syncthreads();
  int i = blockIdx.x * blockDim.x + threadIdx.x;
  if (i >= N) return;
  float px = pos[3*i+0], py = pos[3*i+1], pz = pos[3*i+2];
  float p2 = __fadd_rn(__fadd_rn(__fmul_rn(px,px), __fmul_rn(py,py)), __fmul_rn(pz,pz));
  int b = batch[i];
  int mlo = batchStartC[b], mhi = batchStartC[b+1];
  float best = 3.402823466e+38f;
  int bm = mlo;
  for (int m = mlo; m < mhi; m++){
    float4 c = sc[m];
    float dot = __fadd_rn(__fadd_rn(__fmul_rn(px,c.x), __fmul_rn(py,c.y)),
                          __fmul_rn(pz,c.z));
    float d2  = __fadd_rn(__fsub_rn(p2, __fmul_rn(2.0f, dot)), c.w);
    if (d2 < best){ best = d2; bm = m; }
  }
  unsigned* dst = encMax + bm * FDIM;
  const float4* xi = (const float4*)(x + (size_t)i * FDIM);
  #pragma unroll
  for (int f4 = 0; f4 < FDIM/4; f4++){
    float4 xv = xi[f4];
    atomicMax(&dst[4*f4+0], encf(xv.x));
    atomicMax(&dst[4*f4+1], encf(xv.y));
    atomicMax(&dst[4*f4+2], encf(xv.z));
    atomicMax(&dst[4*f4+3], encf(xv.w));
  }
}
__global__ __launch_bounds__(256) void k_decode(const unsigned* __restrict__ encMax,
    float* __restrict__ outX){
  int t = blockIdx.x * blockDim.x + threadIdx.x;
  if (t >= MMAX * FDIM) return;
  unsigned e = encMax[t];
  outX[t] = (e == 0u) ? 0.0f : decf(e);
}

// ---- workspace layout (bytes) ----
// 0      : startEnc      3 x u32   (memset 0xFF)
// 16     : batchCnt      4 x i32   (memset 0)
// 32     : batchPtr      5 x i32
// 64     : Mout          1 x i32
// 80     : batchStartC   5 x i32
// 128    : counts        2048 x i32
// 8320   : voxBase       2048 x i32
// 16512  : sum_pos       2048 x 3 x f32  [aliased after k_cent: clustCnt | clustBase | cur]
// 41088  : idxOfCluster  1024 x i32
// 45184  : cent4         1024 x float4
// 61568  : encMax 256KB  (fallback)  [fast path: gsum ngroups x 2048 x i32 <= 256KB]
// 323712 : vox           N x i32
// then   : chunkHist     nchunksP x 2048 x i32
// then   : pos_sorted    N x 3 x f32     [aliased after k_sum2: assign(N) | idx_sorted(N)]

extern "C" void kernel_launch(void* const* d_in, const int* in_sizes, int n_in,
                              void* d_out, int out_size, void* d_ws, size_t ws_size,
                              hipStream_t stream){
  const float* pos   = (const float*)d_in[0];
  const float* x     = (const float*)d_in[1];
  const int*   batch = (const int*)d_in[2];
  const int N = in_sizes[2];

  char* w = (char*)d_ws;
  unsigned* startEnc     = (unsigned*)(w + 0);
  int*      batchCnt     = (int*)(w + 16);
  int*      batchPtr     = (int*)(w + 32);
  int*      Mout         = (int*)(w + 64);
  int*      batchStartC  = (int*)(w + 80);
  int*      counts       = (int*)(w + 128);
  int*      voxBase      = (int*)(w + 8320);
  float*    sum_pos      = (float*)(w + 16512);
  int*      idxOfCluster = (int*)(w + 41088);
  float4*   cent4        = (float4*)(w + 45184);
  unsigned* encMax       = (unsigned*)(w + 61568);
  int*      gsum         = (int*)(w + 61568);   // fast path alias of encMax
  int*      vox          = (int*)(w + 323712);
  size_t voxEnd = 323712 + (size_t)N * 4;
  size_t chOff  = (voxEnd + 15) & ~(size_t)15;

  // pick phase-1 sort chunk size based on available workspace
  int chunkP = 256;
  int nchunksP = (N + chunkP - 1) / chunkP;
  size_t psOff = chOff + (size_t)nchunksP * NVOX * 4;
  size_t need  = psOff + (size_t)N * 3 * 4;
  bool fast = true;
  if (ws_size < need || (nchunksP + GRP - 1) / GRP > 32){
    chunkP = 1024;
    nchunksP = (N + chunkP - 1) / chunkP;
    psOff = chOff + (size_t)nchunksP * NVOX * 4;
    need  = psOff + (size_t)N * 3 * 4;
    if (ws_size < need || (nchunksP + GRP - 1) / GRP > 32) fast = false;
  }
  int ngroups = (nchunksP + GRP - 1) / GRP;
  int*   chunkHist  = (int*)(w + chOff);
  float* pos_sorted = (float*)(w + psOff);

  // aliases (fast path only; all orderings are stream-serial)
  int* clustCnt   = (int*)sum_pos;            // after k_cent
  int* clustBase  = (int*)sum_pos + MMAX;
  int* cur        = (int*)sum_pos + 2*MMAX;
  int* assign     = (int*)pos_sorted;         // after k_sum2
  int* idx_sorted = (int*)pos_sorted + N;

  float* outX     = (float*)d_out;          // [1024,64]
  float* outC     = outX + MMAX * FDIM;     // [1024,3]
  float* outNB    = outC + MMAX * 3;        // [1024]
  float* outValid = outNB + MMAX;           // [1024]

  hipMemsetAsync(startEnc, 0xFF, 12, stream);
  hipMemsetAsync(batchCnt, 0, 16, stream);

  const int nb  = (N + 255) / 256;
  k_min_hist<<<256, 256, 0, stream>>>(pos, batch, N, startEnc, batchCnt);
  if (fast){
    k_vox_hist<<<nchunksP, 256, 0, stream>>>(pos, batch, N, startEnc, chunkP,
                                             vox, chunkHist);
    k_gsum<<<ngroups * 8, 256, 0, stream>>>(nchunksP, ngroups, chunkHist, gsum);
    k_gscan<<<NVOX / 256, 256, 0, stream>>>(ngroups, gsum, counts);
    k_colwrite<<<ngroups * 8, 256, 0, stream>>>(nchunksP, ngroups, chunkHist, gsum);
    k_scan<<<1, 64, 0, stream>>>(counts, batchCnt, batchPtr, Mout, batchStartC,
                                 idxOfCluster, voxBase);
    k_scatter<<<nchunksP, 64, 0, stream>>>(pos, vox, N, chunkHist, voxBase,
                                           chunkP, pos_sorted);
    k_sum2<<<NVOX / 64, 64, 0, stream>>>(pos_sorted, voxBase, counts, sum_pos);
    k_cent<<<(MMAX + 255) / 256, 256, 0, stream>>>(sum_pos, counts, idxOfCluster, Mout,
                                                   cent4, outC, outNB, outValid);
    hipMemsetAsync(clustCnt, 0, MMAX * 4, stream);   // after k_cent (aliases sum_pos)
    k_argmin2<<<nb, 256, 0, stream>>>(pos, batch, N, cent4, batchStartC,
                                      assign, clustCnt);
    k_cbase2<<<1, 64, 0, stream>>>(clustCnt, clustBase, cur);
    k_scatter2s<<<nb, 256, 0, stream>>>(assign, N, cur, idx_sorted);
    k_xmax<<<MMAX / 4, 256, 0, stream>>>(x, idx_sorted, clustBase, clustCnt, outX);
  } else {
    hipMemsetAsync(counts, 0, NVOX * 4, stream);
    hipMemsetAsync(encMax, 0, MMAX * FDIM * 4, stream);
    k_vox<<<nb, 256, 0, stream>>>(pos, batch, N, startEnc, vox, counts);
    k_scan<<<1, 64, 0, stream>>>(counts, batchCnt, batchPtr, Mout, batchStartC,
                                 idxOfCluster, voxBase);
    k_sum<<<(NVOX + 63) / 64, 64, 0, stream>>>(pos, vox, counts, batchPtr, sum_pos);
    k_cent<<<(MMAX + 255) / 256, 256, 0, stream>>>(sum_pos, counts, idxOfCluster, Mout,
                                                   cent4, outC, outNB, outValid);
    k_assign_slow<<<nb, 256, 0, stream>>>(pos, x, batch, N, cent4, batchStartC, encMax);
    k_decode<<<(MMAX * FDIM + 255) / 256, 256, 0, stream>>>(encMax, outX);
  }
}